// Round 16
// baseline (494.550 us; speedup 1.0000x reference)
//
#include <hip/hip_runtime.h>
#include <hip/hip_bf16.h>
#include <hip/hip_fp16.h>

// ---------------------------------------------------------------------------
// MDTA_FOR_VIDEO_Prompted — full-graph HIP implementation.
// B=2, C=32, H=W=128. fp32 in/out; 3x3 convs via bf16 MFMA implicit GEMM.
// R16: sigcast folded into k3 epilogue (ASMALL now fp32 NHWC from k2);
//      attn_part split into 16 N-chunks (256-block grid). Rest as R15.
// ---------------------------------------------------------------------------

constexpr int B = 2, C = 32, H = 128, W = 128, N = H * W;

using bh8   = __attribute__((ext_vector_type(8))) short;
using f32x4 = __attribute__((ext_vector_type(4))) float;

__device__ __forceinline__ ushort f2bf(float v) {
  __hip_bfloat16 h = __float2bfloat16(v);
  return *(ushort*)&h;
}
__device__ __forceinline__ float bf2f(ushort u) {
  union { unsigned int i; float f; } w; w.i = ((unsigned int)u) << 16; return w.f;
}

// ---------------- prep (+ fused avgpool -> POOLb) ---------------------------
__global__ __launch_bounds__(256) void k_prep(const float* __restrict__ x,
                                              const float* __restrict__ y,
                                              const float* __restrict__ ln_g,
                                              const float* __restrict__ ln_b,
                                              float* __restrict__ cat2,
                                              ushort* __restrict__ xtb,
                                              ushort* __restrict__ cat2b,
                                              float* __restrict__ xn,
                                              ushort* __restrict__ poolb) {
  __shared__ float tile[C][257];
  const int b = blockIdx.y, n0 = blockIdx.x * 256, tid = threadIdx.x;
  const int n = n0 + tid;
  const int prow = blockIdx.x;
  for (int c = 0; c < C; c++) {
    float v = x[(size_t)(b * C + c) * N + n];
    tile[c][tid] = v;
    cat2[(size_t)(b * 64 + c) * N + n] = v;
  }
  __syncthreads();
  {
    float s = 0.f, ss = 0.f;
#pragma unroll
    for (int c = 0; c < C; c++) { const float v = tile[c][tid]; s += v; ss += v * v; }
    const float mu = s * (1.f / C);
    const float var = ss * (1.f / C) - mu * mu;
    const float inv = rsqrtf(var + 1e-5f);
#pragma unroll
    for (int c = 0; c < C; c++)
      xn[(size_t)(b * C + c) * N + n] = (tile[c][tid] - mu) * inv * ln_g[c] + ln_b[c];
  }
  for (int i = tid; i < C * 256; i += 256) {
    int c = i & 31, nl = i >> 5;
    const ushort bv = f2bf(tile[c][nl]);
    xtb[((size_t)b * N + n0 + nl) * 32 + c] = bv;
    cat2b[((size_t)b * N + n0 + nl) * 64 + c] = bv;
  }
  for (int i = tid; i < 2048; i += 256) {
    const int ox = i >> 5, c = i & 31;
    const float pv = 0.25f * (tile[c][2 * ox] + tile[c][2 * ox + 1]
                            + tile[c][128 + 2 * ox] + tile[c][128 + 2 * ox + 1]);
    poolb[((size_t)b * 4096 + prow * 64 + ox) * 64 + c] = f2bf(pv);
  }
  __syncthreads();
  for (int c = 0; c < C; c++) {
    float v = y[(size_t)(b * C + c) * N + n];
    tile[c][tid] = v;
    cat2[(size_t)(b * 64 + 32 + c) * N + n] = v;
  }
  __syncthreads();
  for (int i = tid; i < C * 256; i += 256) {
    int c = i & 31, nl = i >> 5;
    cat2b[((size_t)b * N + n0 + nl) * 64 + 32 + c] = f2bf(tile[c][nl]);
  }
  for (int i = tid; i < 2048; i += 256) {
    const int ox = i >> 5, c = i & 31;
    const float pv = 0.25f * (tile[c][2 * ox] + tile[c][2 * ox + 1]
                            + tile[c][128 + 2 * ox] + tile[c][128 + 2 * ox + 1]);
    poolb[((size_t)b * 4096 + prow * 64 + ox) * 64 + 32 + c] = f2bf(pv);
  }
}

// ---------------- weight pack ----------------------------------------------
struct WEnt { const float* src; ushort* dst; int cout_real, cin_real, kc32, total; };
struct WArgs { WEnt e[5]; };

__global__ __launch_bounds__(256) void k_wpack(WArgs a) {
  const WEnt en = a.e[blockIdx.y];
  const int tk = 9 * en.kc32;
  for (int i = blockIdx.x * 256 + threadIdx.x; i < en.total; i += gridDim.x * 256) {
    const int co = i / tk, rem = i - co * tk;
    const int t = rem / en.kc32, ci = rem - t * en.kc32;
    float v = 0.f;
    if (co < en.cout_real && ci < en.cin_real)
      v = en.src[((size_t)co * en.cin_real + ci) * 9 + t];
    en.dst[i] = f2bf(v);
  }
}

// ---------------- 3x3 conv MFMA implicit GEMM ------------------------------
// omode 0: fp32 NCHW. 1: bf16 NHWC (LDS transpose; optional sigmoid gate
// from fp32-NHWC[168] aux at nearest-resized px). 2: fp32 NHWC.
__global__ __launch_bounds__(256)
void k_conv3m(const ushort* __restrict__ xin, long in_bs, int in_cs, int ih, int iw,
              const ushort* __restrict__ wp, int kchunks, int cout_real,
              void* __restrict__ outp, long out_bs, int out_coff,
              int oh, int ow, int pad, int omode, int out_cs, int store_tot,
              const float* __restrict__ gatep) {
  __shared__ ushort smem[17408];
  ushort* xt = smem;
  const int tid = threadIdx.x, b = blockIdx.z;
  const int y0 = blockIdx.x * 2, co0 = blockIdx.y * 64;
  const int wv = tid >> 6, lane = tid & 63;
  const int row_sel = wv >> 1, col0 = (wv & 1) * 64;
  const int q = lane >> 4, n = lane & 15, q8 = q * 8;
  const int kc32 = kchunks * 32;
  const ushort* xb = xin + (size_t)b * in_bs;

  f32x4 acc[4][4];
#pragma unroll
  for (int mt = 0; mt < 4; mt++)
#pragma unroll
    for (int nb = 0; nb < 4; nb++) acc[mt][nb] = (f32x4){0.f, 0.f, 0.f, 0.f};

  for (int cc = 0; cc < kchunks; cc++) {
    __syncthreads();
    for (int i = tid; i < 2080; i += 256) {
      const int qq = i & 3, rc = i >> 2;
      const int r = rc / 130, c = rc - r * 130;
      const int yy = y0 - pad + r, xx = c - pad;
      bh8 v = {0, 0, 0, 0, 0, 0, 0, 0};
      if (yy >= 0 && yy < ih && xx >= 0 && xx < iw)
        v = *(const bh8*)(xb + ((size_t)yy * iw + xx) * in_cs + cc * 32 + qq * 8);
      *(bh8*)&xt[rc * 32 + qq * 8] = v;
    }
    __syncthreads();
#pragma unroll
    for (int t = 0; t < 9; t++) {
      const int dy = t / 3, dx = t - dy * 3;
      bh8 a[4], bb[4];
#pragma unroll
      for (int mt = 0; mt < 4; mt++)
        a[mt] = *(const bh8*)(wp + (size_t)((co0 + mt * 16 + n) * 9 + t) * kc32 + cc * 32 + q8);
#pragma unroll
      for (int nb = 0; nb < 4; nb++)
        bb[nb] = *(const bh8*)&xt[((row_sel + dy) * 130 + col0 + nb * 16 + n + dx) * 32 + q8];
#pragma unroll
      for (int mt = 0; mt < 4; mt++)
#pragma unroll
        for (int nb = 0; nb < 4; nb++)
          acc[mt][nb] = __builtin_amdgcn_mfma_f32_16x16x32_bf16(a[mt], bb[nb], acc[mt][nb], 0, 0, 0);
    }
  }

  const size_t osp = (size_t)oh * ow;
  if (omode == 0) {
    const int oy = y0 + row_sel;
    float* ob = (float*)outp + (size_t)b * out_bs + (size_t)out_coff * osp + (size_t)oy * ow;
#pragma unroll
    for (int mt = 0; mt < 4; mt++)
#pragma unroll
      for (int r = 0; r < 4; r++) {
        const int co = co0 + mt * 16 + q * 4 + r;
        if (co < cout_real) {
#pragma unroll
          for (int nb = 0; nb < 4; nb++) {
            const int px = col0 + nb * 16 + n;
            if (px < ow) ob[(size_t)co * osp + px] = acc[mt][nb][r];
          }
        }
      }
  } else if (omode == 1) {
    __syncthreads();
#pragma unroll
    for (int mt = 0; mt < 4; mt++)
#pragma unroll
      for (int nb = 0; nb < 4; nb++) {
        const int px = col0 + nb * 16 + n;
        ushort4 o;
        o.x = f2bf(acc[mt][nb][0]); o.y = f2bf(acc[mt][nb][1]);
        o.z = f2bf(acc[mt][nb][2]); o.w = f2bf(acc[mt][nb][3]);
        *(ushort4*)&smem[(row_sel * 128 + px) * 68 + mt * 16 + q * 4] = o;
      }
    __syncthreads();
    {
      const int row = tid >> 7, px = tid & 127;
      const int oy2 = y0 + row;
      const int sc = min(64, store_tot - co0);
      if (px < ow && sc > 0) {
        ushort* dst = (ushort*)outp + ((size_t)b * osp + (size_t)oy2 * ow + px) * out_cs
                      + out_coff + co0;
        const ushort* src = &smem[(row * 128 + px) * 68];
        if (gatep) {
          const int iy = (oy2 * 62) >> 7, ix2 = (px * 62) >> 7;
          const float* gp = gatep + ((size_t)b * 3844 + iy * 62 + ix2) * 168;
          for (int c = 0; c < sc; c += 4) {
            ushort4 v = *(const ushort4*)(src + c);
            const int ch0 = out_coff + co0 + c;
            float g0 = 1.f, g1 = 1.f, g2 = 1.f, g3 = 1.f;
            if (ch0 + 3 < 166) {
              const float4 a4 = *(const float4*)(gp + ch0);
              g0 = 1.f / (1.f + expf(-a4.x)); g1 = 1.f / (1.f + expf(-a4.y));
              g2 = 1.f / (1.f + expf(-a4.z)); g3 = 1.f / (1.f + expf(-a4.w));
            } else {
              if (ch0 + 0 < 166) g0 = 1.f / (1.f + expf(-gp[ch0 + 0]));
              if (ch0 + 1 < 166) g1 = 1.f / (1.f + expf(-gp[ch0 + 1]));
              if (ch0 + 2 < 166) g2 = 1.f / (1.f + expf(-gp[ch0 + 2]));
              if (ch0 + 3 < 166) g3 = 1.f / (1.f + expf(-gp[ch0 + 3]));
            }
            v.x = f2bf(bf2f(v.x) * g0); v.y = f2bf(bf2f(v.y) * g1);
            v.z = f2bf(bf2f(v.z) * g2); v.w = f2bf(bf2f(v.w) * g3);
            *(ushort4*)(dst + c) = v;
          }
        } else {
          for (int c = 0; c < sc; c += 4)
            *(ushort4*)(dst + c) = *(const ushort4*)(src + c);
        }
      }
    }
  } else {
    float* tf = (float*)smem;
    for (int round = 0; round < 2; round++) {
      __syncthreads();
      if (row_sel == round) {
#pragma unroll
        for (int mt = 0; mt < 4; mt++)
#pragma unroll
          for (int nb = 0; nb < 4; nb++) {
            const int px = col0 + nb * 16 + n;
            *(f32x4*)&tf[px * 66 + mt * 16 + q * 4] = acc[mt][nb];
          }
      }
      __syncthreads();
      const int px = tid & 127, ch = tid >> 7;
      const int oy2 = y0 + round;
      if (px < ow) {
        float* dst = (float*)outp + ((size_t)b * osp + (size_t)oy2 * ow + px) * out_cs
                     + out_coff + co0 + ch * 32;
        const float* src = &tf[px * 66 + ch * 32];
        for (int c = 0; c < 32; c += 4) {
          if (co0 + ch * 32 + c + 3 < store_tot)
            *(float4*)(dst + c) = *(const float4*)(src + c);
        }
      }
    }
  }
}

// ---------------- 1x1 conv: PX px/thread, 4 couts --------------------------
template <int PX>
__global__ __launch_bounds__(256)
void k_conv1x1v(const float* __restrict__ in, long in_bs, int cin,
                const float* __restrict__ wts, const float* __restrict__ bias,
                float* __restrict__ out, long out_bs, int out_coff,
                ushort* __restrict__ outb, int ob_cs) {
  const int n0 = (blockIdx.x * 256 + threadIdx.x) * PX;
  const int co0 = blockIdx.y * 4, b = blockIdx.z;
  const float* ip = in + (size_t)b * in_bs + n0;
  const float* w = wts + (size_t)co0 * cin;
  float acc[4][PX] = {};
  for (int ci = 0; ci < cin; ci++) {
    float xv[PX];
    if (PX == 4) {
      const float4 v = *(const float4*)(ip + (size_t)ci * N);
      xv[0] = v.x; xv[1] = v.y; xv[2] = v.z; xv[3] = v.w;
    } else {
      const float2 v = *(const float2*)(ip + (size_t)ci * N);
      xv[0] = v.x; xv[1] = v.y;
    }
    const float w0 = w[ci], w1 = w[cin + ci], w2 = w[2 * cin + ci], w3 = w[3 * cin + ci];
#pragma unroll
    for (int p = 0; p < PX; p++) {
      acc[0][p] += xv[p] * w0; acc[1][p] += xv[p] * w1;
      acc[2][p] += xv[p] * w2; acc[3][p] += xv[p] * w3;
    }
  }
  if (bias) {
#pragma unroll
    for (int o = 0; o < 4; o++) {
      const float bv = bias[co0 + o];
#pragma unroll
      for (int p = 0; p < PX; p++) acc[o][p] += bv;
    }
  }
  if (outb) {
#pragma unroll
    for (int p = 0; p < PX; p++) {
      ushort4 o;
      o.x = f2bf(acc[0][p]); o.y = f2bf(acc[1][p]);
      o.z = f2bf(acc[2][p]); o.w = f2bf(acc[3][p]);
      *(ushort4*)(outb + ((size_t)b * N + n0 + p) * ob_cs + out_coff + co0) = o;
    }
  } else {
#pragma unroll
    for (int o = 0; o < 4; o++) {
      if (PX == 4)
        *(float4*)(out + (size_t)b * out_bs + (size_t)(out_coff + co0 + o) * N + n0) =
            make_float4(acc[o][0], acc[o][1], acc[o][2], acc[o][3]);
      else
        *(float2*)(out + (size_t)b * out_bs + (size_t)(out_coff + co0 + o) * N + n0) =
            make_float2(acc[o][0], acc[o][1]);
    }
  }
}

// ---------------- grouped 3x3 conv: 4 px/thread ----------------------------
__global__ __launch_bounds__(256) void k_dwconv(const float* __restrict__ in,
                                                const float* __restrict__ wts,
                                                float* __restrict__ out) {
  const int n0 = (blockIdx.x * 256 + threadIdx.x) * 4;
  const int g = blockIdx.y, b = blockIdx.z;
  const int h0 = n0 >> 7, w0 = n0 & 127;
  float acc[3][4] = {};
  for (int ci = 0; ci < 3; ci++) {
    const float* ip = in + ((size_t)b * 96 + g * 3 + ci) * N;
    float v[3][6];
#pragma unroll
    for (int r = 0; r < 3; r++) {
      const int iy = h0 - 1 + r;
      const bool rowok = (iy >= 0) & (iy < H);
#pragma unroll
      for (int j = 0; j < 6; j++) {
        const int ix = w0 - 1 + j;
        v[r][j] = (rowok && ix >= 0 && ix < W) ? ip[(size_t)iy * W + ix] : 0.f;
      }
    }
#pragma unroll
    for (int o = 0; o < 3; o++) {
      const float* wp = wts + ((size_t)(g * 3 + o) * 3 + ci) * 9;
#pragma unroll
      for (int r = 0; r < 3; r++) {
        const float wa = wp[r * 3 + 0], wb = wp[r * 3 + 1], wc = wp[r * 3 + 2];
#pragma unroll
        for (int p = 0; p < 4; p++)
          acc[o][p] += v[r][p] * wa + v[r][p + 1] * wb + v[r][p + 2] * wc;
      }
    }
  }
#pragma unroll
  for (int o = 0; o < 3; o++)
    *(float4*)(out + ((size_t)b * 96 + g * 3 + o) * N + n0) =
        make_float4(acc[o][0], acc[o][1], acc[o][2], acc[o][3]);
}

// ---------------- channel-attn phase 1 (16 N-chunks) -----------------------
template <int DQ>
__global__ __launch_bounds__(256)
void k_attn_part(const float* __restrict__ q1, long q1_bs,
                 const float* __restrict__ q2, long q2_bs,
                 const float* __restrict__ k, long k_bs,
                 float* __restrict__ partial) {
  const int h = blockIdx.x, b = blockIdx.y, ch = blockIdx.z, tid = threadIdx.x;
  const float* qp[DQ];
#pragma unroll
  for (int d = 0; d < DQ; d++) {
    const int qc = h * DQ + d;
    qp[d] = (qc < 32) ? (q1 + (size_t)b * q1_bs + (size_t)qc * N)
                      : (q2 + (size_t)b * q2_bs + (size_t)(qc - 32) * N);
  }
  const float* kp[4];
#pragma unroll
  for (int e = 0; e < 4; e++) kp[e] = k + (size_t)b * k_bs + (size_t)(h * 4 + e) * N;

  constexpr int NV = DQ + 4 + DQ * 4;
  float ssq[DQ] = {}, ssk[4] = {}, gr[DQ][4] = {};
  const int n1 = (ch + 1) * (N / 16);
  for (int n = ch * (N / 16) + tid; n < n1; n += 256) {
    float qv[DQ], kv[4];
#pragma unroll
    for (int d = 0; d < DQ; d++) { qv[d] = qp[d][n]; ssq[d] += qv[d] * qv[d]; }
#pragma unroll
    for (int e = 0; e < 4; e++) { kv[e] = kp[e][n]; ssk[e] += kv[e] * kv[e]; }
#pragma unroll
    for (int d = 0; d < DQ; d++)
#pragma unroll
      for (int e = 0; e < 4; e++) gr[d][e] += qv[d] * kv[e];
  }
  float vals[NV];
#pragma unroll
  for (int d = 0; d < DQ; d++) vals[d] = ssq[d];
#pragma unroll
  for (int e = 0; e < 4; e++) vals[DQ + e] = ssk[e];
#pragma unroll
  for (int d = 0; d < DQ; d++)
#pragma unroll
    for (int e = 0; e < 4; e++) vals[DQ + 4 + d * 4 + e] = gr[d][e];
#pragma unroll
  for (int j = 0; j < NV; j++) {
    float v = vals[j];
    for (int m = 32; m > 0; m >>= 1) v += __shfl_xor(v, m, 64);
    vals[j] = v;
  }
  __shared__ float red[4][NV];
  const int wid = tid >> 6, lane = tid & 63;
  if (lane == 0)
#pragma unroll
    for (int j = 0; j < NV; j++) red[wid][j] = vals[j];
  __syncthreads();
  if (tid < NV)
    partial[(size_t)(((b * 8 + h) * 16) + ch) * NV + tid] =
        red[0][tid] + red[1][tid] + red[2][tid] + red[3][tid];
}

// ---------------- channel-attn phase 2 -------------------------------------
template <int DQ>
__global__ __launch_bounds__(128)
void k_attn_soft(const float* __restrict__ partial,
                 const float* __restrict__ temp, float* __restrict__ stats) {
  constexpr int NV = DQ + 4 + DQ * 4;
  const int h = blockIdx.x, b = blockIdx.y, tid = threadIdx.x;
  __shared__ float tot[NV];
  if (tid < NV) {
    float s = 0.f;
#pragma unroll
    for (int ch = 0; ch < 16; ch++)
      s += partial[(size_t)(((b * 8 + h) * 16) + ch) * NV + tid];
    tot[tid] = s;
  }
  __syncthreads();
  if (tid == 0) {
    float invq[DQ], invk[4];
#pragma unroll
    for (int d = 0; d < DQ; d++) invq[d] = 1.f / fmaxf(sqrtf(tot[d]), 1e-12f);
#pragma unroll
    for (int e = 0; e < 4; e++) invk[e] = 1.f / fmaxf(sqrtf(tot[DQ + e]), 1e-12f);
    const float t = temp[h];
    float* sp = stats + (size_t)(b * 8 + h) * DQ * 4;
    for (int d = 0; d < DQ; d++) {
      float s[4], mx = -1e30f;
#pragma unroll
      for (int e = 0; e < 4; e++) {
        s[e] = tot[DQ + 4 + d * 4 + e] * invq[d] * invk[e] * t;
        mx = fmaxf(mx, s[e]);
      }
      float sum = 0.f;
#pragma unroll
      for (int e = 0; e < 4; e++) { s[e] = expf(s[e] - mx); sum += s[e]; }
#pragma unroll
      for (int e = 0; e < 4; e++) sp[d * 4 + e] = s[e] / sum;
    }
  }
}

// ---------------- fold: M[co][h*4+e] = sum_d w[co][h*DQ+d] * A[h][d][e] ----
template <int DQ>
__global__ __launch_bounds__(256)
void k_fold(const float* __restrict__ stats, const float* __restrict__ w,
            float* __restrict__ M) {
  const int b = blockIdx.x;
  for (int idx = threadIdx.x; idx < 1024; idx += 256) {
    const int co = idx >> 5, j = idx & 31;
    const int h = j >> 2, e = j & 3;
    const float* A = stats + ((size_t)b * 8 + h) * DQ * 4;
    const float* wr = w + co * (8 * DQ) + h * DQ;
    float s = 0.f;
#pragma unroll
    for (int d = 0; d < DQ; d++) s += wr[d] * A[d * 4 + e];
    M[((size_t)b * 32 + co) * 32 + j] = s;
  }
}

// ---------------- folded inner attn+mproj+residual -> CAT1b ----------------
__global__ __launch_bounds__(256)
void k_attn_mproj2(const float* __restrict__ qkv2, const float* __restrict__ M2,
                   const float* __restrict__ x, ushort* __restrict__ cat1b) {
  __shared__ float mls[512];
  const int tid = threadIdx.x, b = blockIdx.y, z = blockIdx.z;
  const int n = blockIdx.x * 256 + tid;
  for (int i = tid; i < 512; i += 256)
    mls[i] = M2[((size_t)b * 32 + z * 16) * 32 + i];
  __syncthreads();
  const float* vi = qkv2 + (size_t)b * (96L * N) + 64L * N;
  float vv[32];
#pragma unroll
  for (int ci = 0; ci < 32; ci++) vv[ci] = vi[(size_t)ci * N + n];
  ushort to[16];
  for (int o = 0; o < 16; o++) {
    const float* m = &mls[o * 32];
    float r = 0.f;
#pragma unroll
    for (int ci = 0; ci < 32; ci += 4) {
      const float4 w4 = *(const float4*)&m[ci];
      r += w4.x * vv[ci] + w4.y * vv[ci + 1] + w4.z * vv[ci + 2] + w4.w * vv[ci + 3];
    }
    r += x[(size_t)(b * 64 + z * 16 + o) * N + n];
    to[o] = f2bf(r);
  }
  ushort* dp = cat1b + ((size_t)b * N + n) * 96 + 64 + z * 16;
#pragma unroll
  for (int k = 0; k < 2; k++) *(bh8*)(dp + k * 8) = *(const bh8*)&to[k * 8];
}

// ---------------- folded final attn+po -> d_out ----------------------------
__global__ __launch_bounds__(256)
void k_attn_po2(const float* __restrict__ cat2, const float* __restrict__ M,
                float* __restrict__ outp) {
  __shared__ float mls[512];
  const int tid = threadIdx.x, b = blockIdx.y, z = blockIdx.z;
  const int n = blockIdx.x * 256 + tid;
  for (int i = tid; i < 512; i += 256)
    mls[i] = M[((size_t)b * 32 + z * 16) * 32 + i];
  __syncthreads();
  const float* v = cat2 + (size_t)b * (64L * N);
  float vv[32];
#pragma unroll
  for (int ci = 0; ci < 32; ci++) vv[ci] = v[(size_t)ci * N + n];
  for (int o = 0; o < 16; o++) {
    const float* m = &mls[o * 32];
    float r = 0.f;
#pragma unroll
    for (int ci = 0; ci < 32; ci += 4) {
      const float4 w4 = *(const float4*)&m[ci];
      r += w4.x * vv[ci] + w4.y * vv[ci + 1] + w4.z * vv[ci + 2] + w4.w * vv[ci + 3];
    }
    outp[(size_t)(b * 32 + z * 16 + o) * N + n] = r;
  }
}

// ---------------- deformable conv v7 ---------------------------------------
__global__ __launch_bounds__(256)
void k_deform7(const ushort* __restrict__ xtb, const float* __restrict__ offs,
               const float* __restrict__ wd3, const float* __restrict__ bd3,
               const float* __restrict__ wd5, const float* __restrict__ bd5,
               const float* __restrict__ wd7, const float* __restrict__ bd7,
               float* __restrict__ out) {
  const int tid = threadIdx.x, b = blockIdx.y;
  const int zone = blockIdx.x >> 9;
  const int blk = blockIdx.x & 511;
  int K, off_c0, out_c0;
  const float *wd, *bd;
  if (zone == 0)      { K = 3; off_c0 = 0;  out_c0 = 0;  wd = wd3; bd = bd3; }
  else if (zone == 1) { K = 5; off_c0 = 18; out_c0 = 32; wd = wd5; bd = bd5; }
  else                { K = 7; off_c0 = 68; out_c0 = 64; wd = wd7; bd = bd7; }
  const int K2 = K * K, PAD = K / 2;

  extern __shared__ __align__(16) char smem[];
  __half*  wlds = (__half*)smem;
  __half*  wbl  = wlds + K2 * 128;
  ushort*  abl  = (ushort*)(wbl + 32 * K2 * 4);

  for (int i = tid; i < K2 * 128; i += 256) {
    const int t = i >> 7, r = i & 127;
    const int g = r >> 4, oo = (r >> 2) & 3, ci = r & 3;
    wlds[i] = __float2half(wd[(size_t)((g * 4 + oo) * 4 + ci) * K2 + t]);
  }
  const int px0 = blk * 32;
  const float* obb = offs + ((size_t)b * N) * 168;
  for (int i = tid; i < 32 * K2; i += 256) {
    const int p = i / K2, t = i - p * K2;
    const int px = px0 + p;
    const int hy = px >> 7, wx = px & 127;
    const int ky = t / K, kx = t - ky * K;
    const float* ob2 = obb + (size_t)px * 168 + off_c0;
    const float dy = ob2[2 * t];
    const float dx = ob2[2 * t + 1];
    const float py = (float)(hy - PAD + ky) + dy;
    const float pxf = (float)(wx - PAD + kx) + dx;
    const float y0f = floorf(py), x0f = floorf(pxf);
    const float fy = py - y0f, fx = pxf - x0f;
    const int y0 = (int)y0f, x0 = (int)x0f;
    const int y1 = y0 + 1, x1 = x0 + 1;
    float w00 = (1.f - fy) * (1.f - fx), w01 = (1.f - fy) * fx;
    float w10 = fy * (1.f - fx), w11 = fy * fx;
    const bool vy0 = (y0 >= 0) & (y0 < H), vy1 = (y1 >= 0) & (y1 < H);
    const bool vx0 = (x0 >= 0) & (x0 < W), vx1 = (x1 >= 0) & (x1 < W);
    w00 = (vy0 & vx0) ? w00 : 0.f;
    w01 = (vy0 & vx1) ? w01 : 0.f;
    w10 = (vy1 & vx0) ? w10 : 0.f;
    w11 = (vy1 & vx1) ? w11 : 0.f;
    const int cy0 = min(max(y0, 0), H - 1), cy1 = min(max(y1, 0), H - 1);
    const int cx0 = min(max(x0, 0), W - 1), cx1 = min(max(x1, 0), W - 1);
    const int base = (p * K2 + t) * 4;
    wbl[base + 0] = __float2half(w00); wbl[base + 1] = __float2half(w01);
    wbl[base + 2] = __float2half(w10); wbl[base + 3] = __float2half(w11);
    abl[base + 0] = (ushort)(cy0 * W + cx0);
    abl[base + 1] = (ushort)(cy0 * W + cx1);
    abl[base + 2] = (ushort)(cy1 * W + cx0);
    abl[base + 3] = (ushort)(cy1 * W + cx1);
  }
  __syncthreads();

  const int pxl = tid >> 3, g = tid & 7;
  const int px = px0 + pxl;
  const ushort* xb = xtb + (size_t)b * N * 32 + g * 4;
  float acc[4] = {0.f, 0.f, 0.f, 0.f};
  for (int t = 0; t < K2; t++) {
    const int base = (pxl * K2 + t) * 4;
    const ushort4 r4 = *(const ushort4*)&abl[base];
    const float2 w01v = __half22float2(*(const __half2*)&wbl[base]);
    const float2 w23v = __half22float2(*(const __half2*)&wbl[base + 2]);
    const ushort4 c0 = *(const ushort4*)(xb + (size_t)r4.x * 32);
    const ushort4 c1 = *(const ushort4*)(xb + (size_t)r4.y * 32);
    const ushort4 c2 = *(const ushort4*)(xb + (size_t)r4.z * 32);
    const ushort4 c3 = *(const ushort4*)(xb + (size_t)r4.w * 32);
    const float s0 = w01v.x * bf2f(c0.x) + w01v.y * bf2f(c1.x)
                   + w23v.x * bf2f(c2.x) + w23v.y * bf2f(c3.x);
    const float s1 = w01v.x * bf2f(c0.y) + w01v.y * bf2f(c1.y)
                   + w23v.x * bf2f(c2.y) + w23v.y * bf2f(c3.y);
    const float s2 = w01v.x * bf2f(c0.z) + w01v.y * bf2f(c1.z)
                   + w23v.x * bf2f(c2.z) + w23v.y * bf2f(c3.z);
    const float s3 = w01v.x * bf2f(c0.w) + w01v.y * bf2f(c1.w)
                   + w23v.x * bf2f(c2.w) + w23v.y * bf2f(c3.w);
    const __half2* wp2 = (const __half2*)&wlds[(t * 8 + g) * 16];
#pragma unroll
    for (int oo = 0; oo < 4; oo++) {
      const float2 u01 = __half22float2(wp2[oo * 2]);
      const float2 u23 = __half22float2(wp2[oo * 2 + 1]);
      acc[oo] += s0 * u01.x + s1 * u01.y + s2 * u23.x + s3 * u23.y;
    }
  }
#pragma unroll
  for (int oo = 0; oo < 4; oo++) {
    const float r = fmaxf(acc[oo] + bd[g * 4 + oo], 0.f);
    out[((size_t)b * 96 + out_c0 + g * 4 + oo) * N + px] = r;
  }
}

// ---------------------------------------------------------------------------
extern "C" void kernel_launch(void* const* d_in, const int* in_sizes, int n_in,
                              void* d_out, int out_size, void* d_ws, size_t ws_size,
                              hipStream_t stream) {
  const float* fx       = (const float*)d_in[0];
  const float* fy       = (const float*)d_in[1];
  const float* w_temp   = (const float*)d_in[2];
  const float* w_po     = (const float*)d_in[3];
  const float* w_lp1    = (const float*)d_in[4];
  const float* w_lp2    = (const float*)d_in[5];
  const float* ln_g     = (const float*)d_in[6];
  const float* ln_b     = (const float*)d_in[7];
  const float* w_tempin = (const float*)d_in[8];
  const float* w_qkv    = (const float*)d_in[9];
  const float* w_qkvd   = (const float*)d_in[10];
  const float* w_mproj  = (const float*)d_in[11];
  const float* w_c3     = (const float*)d_in[12];
  const float* w_k2     = (const float*)d_in[13];
  const float* w_k3     = (const float*)d_in[14];
  const float* w_k4     = (const float*)d_in[15];
  const float* w_d3     = (const float*)d_in[16];
  const float* b_d3     = (const float*)d_in[17];
  const float* w_d5     = (const float*)d_in[18];
  const float* b_d5     = (const float*)d_in[19];
  const float* w_d7     = (const float*)d_in[20];
  const float* b_d7     = (const float*)d_in[21];
  const float* w_pw     = (const float*)d_in[22];
  const float* b_pw     = (const float*)d_in[23];
  float* ws = (float*)d_ws;

  size_t off = 0;
  auto buf = [&](size_t nelem) { float* p = ws + off; off += nelem; return p; };
  float* CAT2   = buf(2097152);
  float* XTBf   = buf(1048576);
  float* R1     = buf(1048576);
  float* R2     = buf(3145728);   // QKV1 -> T3b(bf16,192)
  float* R3     = buf(3145728);   // QKV2 -> ASMALL (fp32 NHWC [B,3844,168])
  float* PROMPT = buf(1048576);
  float* R4     = buf(5439488);   // CAT3 + KFEAT
  float* OFFS   = buf(5505024);   // CAT1b(bf16,96) -> OFFS fp32 NHWC [B,N,168]
  float* STATS  = buf(65536);
  float* CAT2Bf = buf(524288);
  float* WPf    = buf(327680);
  float* POOLBf = buf(262144);
  (void)ws_size; (void)out_size; (void)n_in; (void)in_sizes;

  float* XN = R1;
  float* QKV1 = R2;
  float* QKV2 = R3;   float* ASMALL = R3 + 524288;   // 2.58M fl fits (3.14M region)
  float* CAT3 = R4;   float* KFEAT = R4 + 3145728;
  float* ST_IN = STATS;            // 256
  float* ST_FI = STATS + 256;      // 512
  float* M_IN  = STATS + 1024;     // 2048
  float* M_FI  = STATS + 3072;     // 2048
  float* P_IN  = STATS + 5120;     // 2*8*16*36 = 9216
  float* P_FI  = STATS + 14336;    // 2*8*16*76 = 19456 (ends 33792)

  ushort* XTb   = (ushort*)XTBf;
  ushort* CAT2b = (ushort*)CAT2Bf;
  ushort* POOLb = (ushort*)POOLBf;
  ushort* CAT1b = (ushort*)OFFS;
  ushort* T3b   = (ushort*)R2;     // [B,N,192] bf16 (QKV1 dead by then)

  ushort* WPu = (ushort*)WPf;
  ushort* wp_lp2 = WPu;
  ushort* wp_c3  = wp_lp2 + 18432;
  ushort* wp_k2  = wp_c3 + 55296;
  ushort* wp_k3  = wp_k2 + 110592;
  ushort* wp_k4  = wp_k3 + 110592;

  const long bs64 = 64L * N, bs32 = 32L * N, bs96 = 96L * N;

  WArgs wa;
  wa.e[0] = { w_lp2, wp_lp2, 32, 32, 32, 64 * 9 * 32 };
  wa.e[1] = { w_c3,  wp_c3,  32, 96, 96, 64 * 9 * 96 };
  wa.e[2] = { w_k2,  wp_k2, 166, 64, 64, 192 * 9 * 64 };
  wa.e[3] = { w_k3,  wp_k3, 166, 64, 64, 192 * 9 * 64 };
  wa.e[4] = { w_k4,  wp_k4, 166, 166, 192, 192 * 9 * 192 };
  k_wpack<<<dim3(64, 5), 256, 0, stream>>>(wa);
  k_prep<<<dim3(N / 256, B), 256, 0, stream>>>(
      fx, fy, ln_g, ln_b, CAT2, XTb, CAT2b, XN, POOLb);
  k_conv1x1v<4><<<dim3(N / 1024, 24, B), 256, 0, stream>>>(
      XN, bs32, 32, w_qkv, nullptr, QKV1, bs96, 0, nullptr, 0);
  k_dwconv<<<dim3(N / 1024, 32, B), 256, 0, stream>>>(QKV1, w_qkvd, QKV2);
  k_attn_part<4><<<dim3(8, B, 16), 256, 0, stream>>>(
      QKV2, bs96, nullptr, 0, QKV2 + bs32, bs96, P_IN);
  k_attn_soft<4><<<dim3(8, B), 128, 0, stream>>>(P_IN, w_tempin, ST_IN);
  k_fold<4><<<dim3(B), 256, 0, stream>>>(ST_IN, w_mproj, M_IN);
  k_attn_mproj2<<<dim3(N / 256, B, 2), 256, 0, stream>>>(QKV2, M_IN, CAT2, CAT1b);
  k_conv1x1v<2><<<dim3(N / 512, 8, B), 256, 0, stream>>>(
      CAT2, bs64, 32, w_lp1, nullptr, nullptr, 0, 0, CAT1b, 96);
  k_conv3m<<<dim3(64, 1, B), 256, 0, stream>>>(
      CAT2b, (long)N * 64, 64, H, W, wp_lp2, 1, 32, CAT1b, 0, 32, H, W, 1, 1, 96, 32,
      nullptr);
  k_conv3m<<<dim3(64, 1, B), 256, 0, stream>>>(
      CAT1b, (long)N * 96, 96, H, W, wp_c3, 3, 32, PROMPT, bs32, 0, H, W, 1, 0, 0, 0,
      nullptr);
  // k2 -> ASMALL fp32 NHWC [B,3844,168] (gate source)
  k_conv3m<<<dim3(31, 3, B), 256, 0, stream>>>(
      POOLb, 4096L * 64, 64, 64, 64, wp_k2, 2, 166, ASMALL, 0, 0, 62, 62, 0, 2, 168, 168,
      nullptr);
  // k3 -> T3b bf16 NHWC with fused sigmoid gating (replaces sigcast)
  k_conv3m<<<dim3(64, 3, B), 256, 0, stream>>>(
      CAT2b, (long)N * 64, 64, H, W, wp_k3, 2, 166, T3b, 0, 0, H, W, 1, 1, 192, 192,
      ASMALL);
  // k4 -> OFFS fp32 NHWC [B,N,168]
  k_conv3m<<<dim3(64, 3, B), 256, 0, stream>>>(
      T3b, (long)N * 192, 192, H, W, wp_k4, 6, 166, OFFS, 0, 0, H, W, 1, 2, 168, 168,
      nullptr);
  // merged deformable conv v7
  {
    const int K2m = 49;
    const size_t smem = (size_t)K2m * 128 * 2 + (size_t)32 * K2m * 4 * 2 * 2;  // 37632
    k_deform7<<<dim3(3 * (N / 32), B), 256, smem, stream>>>(
        XTb, OFFS, w_d3, b_d3, w_d5, b_d5, w_d7, b_d7, CAT3);
  }
  k_conv1x1v<2><<<dim3(N / 512, 8, B), 256, 0, stream>>>(
      CAT3, bs96, 96, w_pw, b_pw, KFEAT, bs32, 0, nullptr, 0);
  k_attn_part<8><<<dim3(8, B, 16), 256, 0, stream>>>(
      CAT2, bs64, PROMPT, bs32, KFEAT, bs32, P_FI);
  k_attn_soft<8><<<dim3(8, B), 128, 0, stream>>>(P_FI, w_temp, ST_FI);
  k_fold<8><<<dim3(B), 256, 0, stream>>>(ST_FI, w_po, M_FI);
  k_attn_po2<<<dim3(N / 256, B, 2), 256, 0, stream>>>(CAT2, M_FI, (float*)d_out);
}

// Round 17
// 441.347 us; speedup vs baseline: 1.1205x; 1.1205x over previous
//
#include <hip/hip_runtime.h>
#include <hip/hip_bf16.h>
#include <hip/hip_fp16.h>

// ---------------------------------------------------------------------------
// MDTA_FOR_VIDEO_Prompted — full-graph HIP implementation.
// B=2, C=32, H=W=128. fp32 in/out; 3x3 convs via bf16 MFMA implicit GEMM.
// R17: conv3m retiled to 32 couts/block (MT=2): k3/k4 grid 384->768 blocks
//      (occupancy 14%->~50%), no wasted MFMA for cout=32 convs. Rest as R16.
// ---------------------------------------------------------------------------

constexpr int B = 2, C = 32, H = 128, W = 128, N = H * W;

using bh8   = __attribute__((ext_vector_type(8))) short;
using f32x4 = __attribute__((ext_vector_type(4))) float;

__device__ __forceinline__ ushort f2bf(float v) {
  __hip_bfloat16 h = __float2bfloat16(v);
  return *(ushort*)&h;
}
__device__ __forceinline__ float bf2f(ushort u) {
  union { unsigned int i; float f; } w; w.i = ((unsigned int)u) << 16; return w.f;
}

// ---------------- prep (+ fused avgpool -> POOLb) ---------------------------
__global__ __launch_bounds__(256) void k_prep(const float* __restrict__ x,
                                              const float* __restrict__ y,
                                              const float* __restrict__ ln_g,
                                              const float* __restrict__ ln_b,
                                              float* __restrict__ cat2,
                                              ushort* __restrict__ xtb,
                                              ushort* __restrict__ cat2b,
                                              float* __restrict__ xn,
                                              ushort* __restrict__ poolb) {
  __shared__ float tile[C][257];
  const int b = blockIdx.y, n0 = blockIdx.x * 256, tid = threadIdx.x;
  const int n = n0 + tid;
  const int prow = blockIdx.x;
  for (int c = 0; c < C; c++) {
    float v = x[(size_t)(b * C + c) * N + n];
    tile[c][tid] = v;
    cat2[(size_t)(b * 64 + c) * N + n] = v;
  }
  __syncthreads();
  {
    float s = 0.f, ss = 0.f;
#pragma unroll
    for (int c = 0; c < C; c++) { const float v = tile[c][tid]; s += v; ss += v * v; }
    const float mu = s * (1.f / C);
    const float var = ss * (1.f / C) - mu * mu;
    const float inv = rsqrtf(var + 1e-5f);
#pragma unroll
    for (int c = 0; c < C; c++)
      xn[(size_t)(b * C + c) * N + n] = (tile[c][tid] - mu) * inv * ln_g[c] + ln_b[c];
  }
  for (int i = tid; i < C * 256; i += 256) {
    int c = i & 31, nl = i >> 5;
    const ushort bv = f2bf(tile[c][nl]);
    xtb[((size_t)b * N + n0 + nl) * 32 + c] = bv;
    cat2b[((size_t)b * N + n0 + nl) * 64 + c] = bv;
  }
  for (int i = tid; i < 2048; i += 256) {
    const int ox = i >> 5, c = i & 31;
    const float pv = 0.25f * (tile[c][2 * ox] + tile[c][2 * ox + 1]
                            + tile[c][128 + 2 * ox] + tile[c][128 + 2 * ox + 1]);
    poolb[((size_t)b * 4096 + prow * 64 + ox) * 64 + c] = f2bf(pv);
  }
  __syncthreads();
  for (int c = 0; c < C; c++) {
    float v = y[(size_t)(b * C + c) * N + n];
    tile[c][tid] = v;
    cat2[(size_t)(b * 64 + 32 + c) * N + n] = v;
  }
  __syncthreads();
  for (int i = tid; i < C * 256; i += 256) {
    int c = i & 31, nl = i >> 5;
    cat2b[((size_t)b * N + n0 + nl) * 64 + 32 + c] = f2bf(tile[c][nl]);
  }
  for (int i = tid; i < 2048; i += 256) {
    const int ox = i >> 5, c = i & 31;
    const float pv = 0.25f * (tile[c][2 * ox] + tile[c][2 * ox + 1]
                            + tile[c][128 + 2 * ox] + tile[c][128 + 2 * ox + 1]);
    poolb[((size_t)b * 4096 + prow * 64 + ox) * 64 + 32 + c] = f2bf(pv);
  }
}

// ---------------- weight pack ----------------------------------------------
struct WEnt { const float* src; ushort* dst; int cout_real, cin_real, kc32, total; };
struct WArgs { WEnt e[5]; };

__global__ __launch_bounds__(256) void k_wpack(WArgs a) {
  const WEnt en = a.e[blockIdx.y];
  const int tk = 9 * en.kc32;
  for (int i = blockIdx.x * 256 + threadIdx.x; i < en.total; i += gridDim.x * 256) {
    const int co = i / tk, rem = i - co * tk;
    const int t = rem / en.kc32, ci = rem - t * en.kc32;
    float v = 0.f;
    if (co < en.cout_real && ci < en.cin_real)
      v = en.src[((size_t)co * en.cin_real + ci) * 9 + t];
    en.dst[i] = f2bf(v);
  }
}

// ---------------- 3x3 conv MFMA implicit GEMM (32 couts/block) -------------
// omode 0: fp32 NCHW. 1: bf16 NHWC via LDS transpose (+optional sigmoid gate
// from fp32-NHWC[168] aux). 2: fp32 NHWC via 2-round LDS transpose.
__global__ __launch_bounds__(256)
void k_conv3m(const ushort* __restrict__ xin, long in_bs, int in_cs, int ih, int iw,
              const ushort* __restrict__ wp, int kchunks, int cout_real,
              void* __restrict__ outp, long out_bs, int out_coff,
              int oh, int ow, int pad, int omode, int out_cs, int store_tot,
              const float* __restrict__ gatep) {
  __shared__ ushort smem[17408];
  ushort* xt = smem;
  const int tid = threadIdx.x, b = blockIdx.z;
  const int y0 = blockIdx.x * 2, co0 = blockIdx.y * 32;
  const int wv = tid >> 6, lane = tid & 63;
  const int row_sel = wv >> 1, col0 = (wv & 1) * 64;
  const int q = lane >> 4, n = lane & 15, q8 = q * 8;
  const int kc32 = kchunks * 32;
  const ushort* xb = xin + (size_t)b * in_bs;

  f32x4 acc[2][4];
#pragma unroll
  for (int mt = 0; mt < 2; mt++)
#pragma unroll
    for (int nb = 0; nb < 4; nb++) acc[mt][nb] = (f32x4){0.f, 0.f, 0.f, 0.f};

  for (int cc = 0; cc < kchunks; cc++) {
    __syncthreads();
    for (int i = tid; i < 2080; i += 256) {
      const int qq = i & 3, rc = i >> 2;
      const int r = rc / 130, c = rc - r * 130;
      const int yy = y0 - pad + r, xx = c - pad;
      bh8 v = {0, 0, 0, 0, 0, 0, 0, 0};
      if (yy >= 0 && yy < ih && xx >= 0 && xx < iw)
        v = *(const bh8*)(xb + ((size_t)yy * iw + xx) * in_cs + cc * 32 + qq * 8);
      *(bh8*)&xt[rc * 32 + qq * 8] = v;
    }
    __syncthreads();
#pragma unroll
    for (int t = 0; t < 9; t++) {
      const int dy = t / 3, dx = t - dy * 3;
      bh8 a[2], bb[4];
#pragma unroll
      for (int mt = 0; mt < 2; mt++)
        a[mt] = *(const bh8*)(wp + (size_t)((co0 + mt * 16 + n) * 9 + t) * kc32 + cc * 32 + q8);
#pragma unroll
      for (int nb = 0; nb < 4; nb++)
        bb[nb] = *(const bh8*)&xt[((row_sel + dy) * 130 + col0 + nb * 16 + n + dx) * 32 + q8];
#pragma unroll
      for (int mt = 0; mt < 2; mt++)
#pragma unroll
        for (int nb = 0; nb < 4; nb++)
          acc[mt][nb] = __builtin_amdgcn_mfma_f32_16x16x32_bf16(a[mt], bb[nb], acc[mt][nb], 0, 0, 0);
    }
  }

  const size_t osp = (size_t)oh * ow;
  if (omode == 0) {
    const int oy = y0 + row_sel;
    float* ob = (float*)outp + (size_t)b * out_bs + (size_t)out_coff * osp + (size_t)oy * ow;
#pragma unroll
    for (int mt = 0; mt < 2; mt++)
#pragma unroll
      for (int r = 0; r < 4; r++) {
        const int co = co0 + mt * 16 + q * 4 + r;
        if (co < cout_real) {
#pragma unroll
          for (int nb = 0; nb < 4; nb++) {
            const int px = col0 + nb * 16 + n;
            if (px < ow) ob[(size_t)co * osp + px] = acc[mt][nb][r];
          }
        }
      }
  } else if (omode == 1) {
    // stage bf16 tile [row(2)][px(128)][co pad 36], per-px contiguous store
    __syncthreads();
#pragma unroll
    for (int mt = 0; mt < 2; mt++)
#pragma unroll
      for (int nb = 0; nb < 4; nb++) {
        const int px = col0 + nb * 16 + n;
        ushort4 o;
        o.x = f2bf(acc[mt][nb][0]); o.y = f2bf(acc[mt][nb][1]);
        o.z = f2bf(acc[mt][nb][2]); o.w = f2bf(acc[mt][nb][3]);
        *(ushort4*)&smem[(row_sel * 128 + px) * 36 + mt * 16 + q * 4] = o;
      }
    __syncthreads();
    {
      const int row = tid >> 7, px = tid & 127;
      const int oy2 = y0 + row;
      const int sc = min(32, store_tot - co0);
      if (px < ow && sc > 0) {
        ushort* dst = (ushort*)outp + ((size_t)b * osp + (size_t)oy2 * ow + px) * out_cs
                      + out_coff + co0;
        const ushort* src = &smem[(row * 128 + px) * 36];
        if (gatep) {
          const int iy = (oy2 * 62) >> 7, ix2 = (px * 62) >> 7;
          const float* gp = gatep + ((size_t)b * 3844 + iy * 62 + ix2) * 168;
          for (int c = 0; c < sc; c += 4) {
            ushort4 v = *(const ushort4*)(src + c);
            const int ch0 = out_coff + co0 + c;
            float g0 = 1.f, g1 = 1.f, g2 = 1.f, g3 = 1.f;
            if (ch0 + 3 < 166) {
              const float4 a4 = *(const float4*)(gp + ch0);
              g0 = 1.f / (1.f + expf(-a4.x)); g1 = 1.f / (1.f + expf(-a4.y));
              g2 = 1.f / (1.f + expf(-a4.z)); g3 = 1.f / (1.f + expf(-a4.w));
            } else {
              if (ch0 + 0 < 166) g0 = 1.f / (1.f + expf(-gp[ch0 + 0]));
              if (ch0 + 1 < 166) g1 = 1.f / (1.f + expf(-gp[ch0 + 1]));
              if (ch0 + 2 < 166) g2 = 1.f / (1.f + expf(-gp[ch0 + 2]));
              if (ch0 + 3 < 166) g3 = 1.f / (1.f + expf(-gp[ch0 + 3]));
            }
            v.x = f2bf(bf2f(v.x) * g0); v.y = f2bf(bf2f(v.y) * g1);
            v.z = f2bf(bf2f(v.z) * g2); v.w = f2bf(bf2f(v.w) * g3);
            *(ushort4*)(dst + c) = v;
          }
        } else {
          for (int c = 0; c < sc; c += 4)
            *(ushort4*)(dst + c) = *(const ushort4*)(src + c);
        }
      }
    }
  } else {
    // fp32 NHWC, two row-rounds: [px(128)][co pad 34]
    float* tf = (float*)smem;
    for (int round = 0; round < 2; round++) {
      __syncthreads();
      if (row_sel == round) {
#pragma unroll
        for (int mt = 0; mt < 2; mt++)
#pragma unroll
          for (int nb = 0; nb < 4; nb++) {
            const int px = col0 + nb * 16 + n;
            *(f32x4*)&tf[px * 34 + mt * 16 + q * 4] = acc[mt][nb];
          }
      }
      __syncthreads();
      const int px = tid & 127, half = tid >> 7;
      const int oy2 = y0 + round;
      if (px < ow) {
        float* dst = (float*)outp + ((size_t)b * osp + (size_t)oy2 * ow + px) * out_cs
                     + out_coff + co0 + half * 16;
        const float* src = &tf[px * 34 + half * 16];
        for (int c = 0; c < 16; c += 4) {
          if (co0 + half * 16 + c + 3 < store_tot)
            *(float4*)(dst + c) = *(const float4*)(src + c);
        }
      }
    }
  }
}

// ---------------- 1x1 conv: PX px/thread, 4 couts --------------------------
template <int PX>
__global__ __launch_bounds__(256)
void k_conv1x1v(const float* __restrict__ in, long in_bs, int cin,
                const float* __restrict__ wts, const float* __restrict__ bias,
                float* __restrict__ out, long out_bs, int out_coff,
                ushort* __restrict__ outb, int ob_cs) {
  const int n0 = (blockIdx.x * 256 + threadIdx.x) * PX;
  const int co0 = blockIdx.y * 4, b = blockIdx.z;
  const float* ip = in + (size_t)b * in_bs + n0;
  const float* w = wts + (size_t)co0 * cin;
  float acc[4][PX] = {};
  for (int ci = 0; ci < cin; ci++) {
    float xv[PX];
    if (PX == 4) {
      const float4 v = *(const float4*)(ip + (size_t)ci * N);
      xv[0] = v.x; xv[1] = v.y; xv[2] = v.z; xv[3] = v.w;
    } else {
      const float2 v = *(const float2*)(ip + (size_t)ci * N);
      xv[0] = v.x; xv[1] = v.y;
    }
    const float w0 = w[ci], w1 = w[cin + ci], w2 = w[2 * cin + ci], w3 = w[3 * cin + ci];
#pragma unroll
    for (int p = 0; p < PX; p++) {
      acc[0][p] += xv[p] * w0; acc[1][p] += xv[p] * w1;
      acc[2][p] += xv[p] * w2; acc[3][p] += xv[p] * w3;
    }
  }
  if (bias) {
#pragma unroll
    for (int o = 0; o < 4; o++) {
      const float bv = bias[co0 + o];
#pragma unroll
      for (int p = 0; p < PX; p++) acc[o][p] += bv;
    }
  }
  if (outb) {
#pragma unroll
    for (int p = 0; p < PX; p++) {
      ushort4 o;
      o.x = f2bf(acc[0][p]); o.y = f2bf(acc[1][p]);
      o.z = f2bf(acc[2][p]); o.w = f2bf(acc[3][p]);
      *(ushort4*)(outb + ((size_t)b * N + n0 + p) * ob_cs + out_coff + co0) = o;
    }
  } else {
#pragma unroll
    for (int o = 0; o < 4; o++) {
      if (PX == 4)
        *(float4*)(out + (size_t)b * out_bs + (size_t)(out_coff + co0 + o) * N + n0) =
            make_float4(acc[o][0], acc[o][1], acc[o][2], acc[o][3]);
      else
        *(float2*)(out + (size_t)b * out_bs + (size_t)(out_coff + co0 + o) * N + n0) =
            make_float2(acc[o][0], acc[o][1]);
    }
  }
}

// ---------------- grouped 3x3 conv: 4 px/thread ----------------------------
__global__ __launch_bounds__(256) void k_dwconv(const float* __restrict__ in,
                                                const float* __restrict__ wts,
                                                float* __restrict__ out) {
  const int n0 = (blockIdx.x * 256 + threadIdx.x) * 4;
  const int g = blockIdx.y, b = blockIdx.z;
  const int h0 = n0 >> 7, w0 = n0 & 127;
  float acc[3][4] = {};
  for (int ci = 0; ci < 3; ci++) {
    const float* ip = in + ((size_t)b * 96 + g * 3 + ci) * N;
    float v[3][6];
#pragma unroll
    for (int r = 0; r < 3; r++) {
      const int iy = h0 - 1 + r;
      const bool rowok = (iy >= 0) & (iy < H);
#pragma unroll
      for (int j = 0; j < 6; j++) {
        const int ix = w0 - 1 + j;
        v[r][j] = (rowok && ix >= 0 && ix < W) ? ip[(size_t)iy * W + ix] : 0.f;
      }
    }
#pragma unroll
    for (int o = 0; o < 3; o++) {
      const float* wp = wts + ((size_t)(g * 3 + o) * 3 + ci) * 9;
#pragma unroll
      for (int r = 0; r < 3; r++) {
        const float wa = wp[r * 3 + 0], wb = wp[r * 3 + 1], wc = wp[r * 3 + 2];
#pragma unroll
        for (int p = 0; p < 4; p++)
          acc[o][p] += v[r][p] * wa + v[r][p + 1] * wb + v[r][p + 2] * wc;
      }
    }
  }
#pragma unroll
  for (int o = 0; o < 3; o++)
    *(float4*)(out + ((size_t)b * 96 + g * 3 + o) * N + n0) =
        make_float4(acc[o][0], acc[o][1], acc[o][2], acc[o][3]);
}

// ---------------- channel-attn phase 1 (16 N-chunks) -----------------------
template <int DQ>
__global__ __launch_bounds__(256)
void k_attn_part(const float* __restrict__ q1, long q1_bs,
                 const float* __restrict__ q2, long q2_bs,
                 const float* __restrict__ k, long k_bs,
                 float* __restrict__ partial) {
  const int h = blockIdx.x, b = blockIdx.y, ch = blockIdx.z, tid = threadIdx.x;
  const float* qp[DQ];
#pragma unroll
  for (int d = 0; d < DQ; d++) {
    const int qc = h * DQ + d;
    qp[d] = (qc < 32) ? (q1 + (size_t)b * q1_bs + (size_t)qc * N)
                      : (q2 + (size_t)b * q2_bs + (size_t)(qc - 32) * N);
  }
  const float* kp[4];
#pragma unroll
  for (int e = 0; e < 4; e++) kp[e] = k + (size_t)b * k_bs + (size_t)(h * 4 + e) * N;

  constexpr int NV = DQ + 4 + DQ * 4;
  float ssq[DQ] = {}, ssk[4] = {}, gr[DQ][4] = {};
  const int n1 = (ch + 1) * (N / 16);
  for (int n = ch * (N / 16) + tid; n < n1; n += 256) {
    float qv[DQ], kv[4];
#pragma unroll
    for (int d = 0; d < DQ; d++) { qv[d] = qp[d][n]; ssq[d] += qv[d] * qv[d]; }
#pragma unroll
    for (int e = 0; e < 4; e++) { kv[e] = kp[e][n]; ssk[e] += kv[e] * kv[e]; }
#pragma unroll
    for (int d = 0; d < DQ; d++)
#pragma unroll
      for (int e = 0; e < 4; e++) gr[d][e] += qv[d] * kv[e];
  }
  float vals[NV];
#pragma unroll
  for (int d = 0; d < DQ; d++) vals[d] = ssq[d];
#pragma unroll
  for (int e = 0; e < 4; e++) vals[DQ + e] = ssk[e];
#pragma unroll
  for (int d = 0; d < DQ; d++)
#pragma unroll
    for (int e = 0; e < 4; e++) vals[DQ + 4 + d * 4 + e] = gr[d][e];
#pragma unroll
  for (int j = 0; j < NV; j++) {
    float v = vals[j];
    for (int m = 32; m > 0; m >>= 1) v += __shfl_xor(v, m, 64);
    vals[j] = v;
  }
  __shared__ float red[4][NV];
  const int wid = tid >> 6, lane = tid & 63;
  if (lane == 0)
#pragma unroll
    for (int j = 0; j < NV; j++) red[wid][j] = vals[j];
  __syncthreads();
  if (tid < NV)
    partial[(size_t)(((b * 8 + h) * 16) + ch) * NV + tid] =
        red[0][tid] + red[1][tid] + red[2][tid] + red[3][tid];
}

// ---------------- channel-attn phase 2 -------------------------------------
template <int DQ>
__global__ __launch_bounds__(128)
void k_attn_soft(const float* __restrict__ partial,
                 const float* __restrict__ temp, float* __restrict__ stats) {
  constexpr int NV = DQ + 4 + DQ * 4;
  const int h = blockIdx.x, b = blockIdx.y, tid = threadIdx.x;
  __shared__ float tot[NV];
  if (tid < NV) {
    float s = 0.f;
#pragma unroll
    for (int ch = 0; ch < 16; ch++)
      s += partial[(size_t)(((b * 8 + h) * 16) + ch) * NV + tid];
    tot[tid] = s;
  }
  __syncthreads();
  if (tid == 0) {
    float invq[DQ], invk[4];
#pragma unroll
    for (int d = 0; d < DQ; d++) invq[d] = 1.f / fmaxf(sqrtf(tot[d]), 1e-12f);
#pragma unroll
    for (int e = 0; e < 4; e++) invk[e] = 1.f / fmaxf(sqrtf(tot[DQ + e]), 1e-12f);
    const float t = temp[h];
    float* sp = stats + (size_t)(b * 8 + h) * DQ * 4;
    for (int d = 0; d < DQ; d++) {
      float s[4], mx = -1e30f;
#pragma unroll
      for (int e = 0; e < 4; e++) {
        s[e] = tot[DQ + 4 + d * 4 + e] * invq[d] * invk[e] * t;
        mx = fmaxf(mx, s[e]);
      }
      float sum = 0.f;
#pragma unroll
      for (int e = 0; e < 4; e++) { s[e] = expf(s[e] - mx); sum += s[e]; }
#pragma unroll
      for (int e = 0; e < 4; e++) sp[d * 4 + e] = s[e] / sum;
    }
  }
}

// ---------------- fold: M[co][h*4+e] = sum_d w[co][h*DQ+d] * A[h][d][e] ----
template <int DQ>
__global__ __launch_bounds__(256)
void k_fold(const float* __restrict__ stats, const float* __restrict__ w,
            float* __restrict__ M) {
  const int b = blockIdx.x;
  for (int idx = threadIdx.x; idx < 1024; idx += 256) {
    const int co = idx >> 5, j = idx & 31;
    const int h = j >> 2, e = j & 3;
    const float* A = stats + ((size_t)b * 8 + h) * DQ * 4;
    const float* wr = w + co * (8 * DQ) + h * DQ;
    float s = 0.f;
#pragma unroll
    for (int d = 0; d < DQ; d++) s += wr[d] * A[d * 4 + e];
    M[((size_t)b * 32 + co) * 32 + j] = s;
  }
}

// ---------------- folded inner attn+mproj+residual -> CAT1b ----------------
__global__ __launch_bounds__(256)
void k_attn_mproj2(const float* __restrict__ qkv2, const float* __restrict__ M2,
                   const float* __restrict__ x, ushort* __restrict__ cat1b) {
  __shared__ float mls[512];
  const int tid = threadIdx.x, b = blockIdx.y, z = blockIdx.z;
  const int n = blockIdx.x * 256 + tid;
  for (int i = tid; i < 512; i += 256)
    mls[i] = M2[((size_t)b * 32 + z * 16) * 32 + i];
  __syncthreads();
  const float* vi = qkv2 + (size_t)b * (96L * N) + 64L * N;
  float vv[32];
#pragma unroll
  for (int ci = 0; ci < 32; ci++) vv[ci] = vi[(size_t)ci * N + n];
  ushort to[16];
  for (int o = 0; o < 16; o++) {
    const float* m = &mls[o * 32];
    float r = 0.f;
#pragma unroll
    for (int ci = 0; ci < 32; ci += 4) {
      const float4 w4 = *(const float4*)&m[ci];
      r += w4.x * vv[ci] + w4.y * vv[ci + 1] + w4.z * vv[ci + 2] + w4.w * vv[ci + 3];
    }
    r += x[(size_t)(b * 64 + z * 16 + o) * N + n];
    to[o] = f2bf(r);
  }
  ushort* dp = cat1b + ((size_t)b * N + n) * 96 + 64 + z * 16;
#pragma unroll
  for (int k = 0; k < 2; k++) *(bh8*)(dp + k * 8) = *(const bh8*)&to[k * 8];
}

// ---------------- folded final attn+po -> d_out ----------------------------
__global__ __launch_bounds__(256)
void k_attn_po2(const float* __restrict__ cat2, const float* __restrict__ M,
                float* __restrict__ outp) {
  __shared__ float mls[512];
  const int tid = threadIdx.x, b = blockIdx.y, z = blockIdx.z;
  const int n = blockIdx.x * 256 + tid;
  for (int i = tid; i < 512; i += 256)
    mls[i] = M[((size_t)b * 32 + z * 16) * 32 + i];
  __syncthreads();
  const float* v = cat2 + (size_t)b * (64L * N);
  float vv[32];
#pragma unroll
  for (int ci = 0; ci < 32; ci++) vv[ci] = v[(size_t)ci * N + n];
  for (int o = 0; o < 16; o++) {
    const float* m = &mls[o * 32];
    float r = 0.f;
#pragma unroll
    for (int ci = 0; ci < 32; ci += 4) {
      const float4 w4 = *(const float4*)&m[ci];
      r += w4.x * vv[ci] + w4.y * vv[ci + 1] + w4.z * vv[ci + 2] + w4.w * vv[ci + 3];
    }
    outp[(size_t)(b * 32 + z * 16 + o) * N + n] = r;
  }
}

// ---------------- deformable conv v7 ---------------------------------------
__global__ __launch_bounds__(256)
void k_deform7(const ushort* __restrict__ xtb, const float* __restrict__ offs,
               const float* __restrict__ wd3, const float* __restrict__ bd3,
               const float* __restrict__ wd5, const float* __restrict__ bd5,
               const float* __restrict__ wd7, const float* __restrict__ bd7,
               float* __restrict__ out) {
  const int tid = threadIdx.x, b = blockIdx.y;
  const int zone = blockIdx.x >> 9;
  const int blk = blockIdx.x & 511;
  int K, off_c0, out_c0;
  const float *wd, *bd;
  if (zone == 0)      { K = 3; off_c0 = 0;  out_c0 = 0;  wd = wd3; bd = bd3; }
  else if (zone == 1) { K = 5; off_c0 = 18; out_c0 = 32; wd = wd5; bd = bd5; }
  else                { K = 7; off_c0 = 68; out_c0 = 64; wd = wd7; bd = bd7; }
  const int K2 = K * K, PAD = K / 2;

  extern __shared__ __align__(16) char smem[];
  __half*  wlds = (__half*)smem;
  __half*  wbl  = wlds + K2 * 128;
  ushort*  abl  = (ushort*)(wbl + 32 * K2 * 4);

  for (int i = tid; i < K2 * 128; i += 256) {
    const int t = i >> 7, r = i & 127;
    const int g = r >> 4, oo = (r >> 2) & 3, ci = r & 3;
    wlds[i] = __float2half(wd[(size_t)((g * 4 + oo) * 4 + ci) * K2 + t]);
  }
  const int px0 = blk * 32;
  const float* obb = offs + ((size_t)b * N) * 168;
  for (int i = tid; i < 32 * K2; i += 256) {
    const int p = i / K2, t = i - p * K2;
    const int px = px0 + p;
    const int hy = px >> 7, wx = px & 127;
    const int ky = t / K, kx = t - ky * K;
    const float* ob2 = obb + (size_t)px * 168 + off_c0;
    const float dy = ob2[2 * t];
    const float dx = ob2[2 * t + 1];
    const float py = (float)(hy - PAD + ky) + dy;
    const float pxf = (float)(wx - PAD + kx) + dx;
    const float y0f = floorf(py), x0f = floorf(pxf);
    const float fy = py - y0f, fx = pxf - x0f;
    const int y0 = (int)y0f, x0 = (int)x0f;
    const int y1 = y0 + 1, x1 = x0 + 1;
    float w00 = (1.f - fy) * (1.f - fx), w01 = (1.f - fy) * fx;
    float w10 = fy * (1.f - fx), w11 = fy * fx;
    const bool vy0 = (y0 >= 0) & (y0 < H), vy1 = (y1 >= 0) & (y1 < H);
    const bool vx0 = (x0 >= 0) & (x0 < W), vx1 = (x1 >= 0) & (x1 < W);
    w00 = (vy0 & vx0) ? w00 : 0.f;
    w01 = (vy0 & vx1) ? w01 : 0.f;
    w10 = (vy1 & vx0) ? w10 : 0.f;
    w11 = (vy1 & vx1) ? w11 : 0.f;
    const int cy0 = min(max(y0, 0), H - 1), cy1 = min(max(y1, 0), H - 1);
    const int cx0 = min(max(x0, 0), W - 1), cx1 = min(max(x1, 0), W - 1);
    const int base = (p * K2 + t) * 4;
    wbl[base + 0] = __float2half(w00); wbl[base + 1] = __float2half(w01);
    wbl[base + 2] = __float2half(w10); wbl[base + 3] = __float2half(w11);
    abl[base + 0] = (ushort)(cy0 * W + cx0);
    abl[base + 1] = (ushort)(cy0 * W + cx1);
    abl[base + 2] = (ushort)(cy1 * W + cx0);
    abl[base + 3] = (ushort)(cy1 * W + cx1);
  }
  __syncthreads();

  const int pxl = tid >> 3, g = tid & 7;
  const int px = px0 + pxl;
  const ushort* xb = xtb + (size_t)b * N * 32 + g * 4;
  float acc[4] = {0.f, 0.f, 0.f, 0.f};
  for (int t = 0; t < K2; t++) {
    const int base = (pxl * K2 + t) * 4;
    const ushort4 r4 = *(const ushort4*)&abl[base];
    const float2 w01v = __half22float2(*(const __half2*)&wbl[base]);
    const float2 w23v = __half22float2(*(const __half2*)&wbl[base + 2]);
    const ushort4 c0 = *(const ushort4*)(xb + (size_t)r4.x * 32);
    const ushort4 c1 = *(const ushort4*)(xb + (size_t)r4.y * 32);
    const ushort4 c2 = *(const ushort4*)(xb + (size_t)r4.z * 32);
    const ushort4 c3 = *(const ushort4*)(xb + (size_t)r4.w * 32);
    const float s0 = w01v.x * bf2f(c0.x) + w01v.y * bf2f(c1.x)
                   + w23v.x * bf2f(c2.x) + w23v.y * bf2f(c3.x);
    const float s1 = w01v.x * bf2f(c0.y) + w01v.y * bf2f(c1.y)
                   + w23v.x * bf2f(c2.y) + w23v.y * bf2f(c3.y);
    const float s2 = w01v.x * bf2f(c0.z) + w01v.y * bf2f(c1.z)
                   + w23v.x * bf2f(c2.z) + w23v.y * bf2f(c3.z);
    const float s3 = w01v.x * bf2f(c0.w) + w01v.y * bf2f(c1.w)
                   + w23v.x * bf2f(c2.w) + w23v.y * bf2f(c3.w);
    const __half2* wp2 = (const __half2*)&wlds[(t * 8 + g) * 16];
#pragma unroll
    for (int oo = 0; oo < 4; oo++) {
      const float2 u01 = __half22float2(wp2[oo * 2]);
      const float2 u23 = __half22float2(wp2[oo * 2 + 1]);
      acc[oo] += s0 * u01.x + s1 * u01.y + s2 * u23.x + s3 * u23.y;
    }
  }
#pragma unroll
  for (int oo = 0; oo < 4; oo++) {
    const float r = fmaxf(acc[oo] + bd[g * 4 + oo], 0.f);
    out[((size_t)b * 96 + out_c0 + g * 4 + oo) * N + px] = r;
  }
}

// ---------------------------------------------------------------------------
extern "C" void kernel_launch(void* const* d_in, const int* in_sizes, int n_in,
                              void* d_out, int out_size, void* d_ws, size_t ws_size,
                              hipStream_t stream) {
  const float* fx       = (const float*)d_in[0];
  const float* fy       = (const float*)d_in[1];
  const float* w_temp   = (const float*)d_in[2];
  const float* w_po     = (const float*)d_in[3];
  const float* w_lp1    = (const float*)d_in[4];
  const float* w_lp2    = (const float*)d_in[5];
  const float* ln_g     = (const float*)d_in[6];
  const float* ln_b     = (const float*)d_in[7];
  const float* w_tempin = (const float*)d_in[8];
  const float* w_qkv    = (const float*)d_in[9];
  const float* w_qkvd   = (const float*)d_in[10];
  const float* w_mproj  = (const float*)d_in[11];
  const float* w_c3     = (const float*)d_in[12];
  const float* w_k2     = (const float*)d_in[13];
  const float* w_k3     = (const float*)d_in[14];
  const float* w_k4     = (const float*)d_in[15];
  const float* w_d3     = (const float*)d_in[16];
  const float* b_d3     = (const float*)d_in[17];
  const float* w_d5     = (const float*)d_in[18];
  const float* b_d5     = (const float*)d_in[19];
  const float* w_d7     = (const float*)d_in[20];
  const float* b_d7     = (const float*)d_in[21];
  const float* w_pw     = (const float*)d_in[22];
  const float* b_pw     = (const float*)d_in[23];
  float* ws = (float*)d_ws;

  size_t off = 0;
  auto buf = [&](size_t nelem) { float* p = ws + off; off += nelem; return p; };
  float* CAT2   = buf(2097152);
  float* XTBf   = buf(1048576);
  float* R1     = buf(1048576);
  float* R2     = buf(3145728);   // QKV1 -> T3b(bf16,192)
  float* R3     = buf(3145728);   // QKV2 -> ASMALL (fp32 NHWC [B,3844,168])
  float* PROMPT = buf(1048576);
  float* R4     = buf(5439488);   // CAT3 + KFEAT
  float* OFFS   = buf(5505024);   // CAT1b(bf16,96) -> OFFS fp32 NHWC [B,N,168]
  float* STATS  = buf(65536);
  float* CAT2Bf = buf(524288);
  float* WPf    = buf(327680);
  float* POOLBf = buf(262144);
  (void)ws_size; (void)out_size; (void)n_in; (void)in_sizes;

  float* XN = R1;
  float* QKV1 = R2;
  float* QKV2 = R3;   float* ASMALL = R3 + 524288;
  float* CAT3 = R4;   float* KFEAT = R4 + 3145728;
  float* ST_IN = STATS;
  float* ST_FI = STATS + 256;
  float* M_IN  = STATS + 1024;
  float* M_FI  = STATS + 3072;
  float* P_IN  = STATS + 5120;
  float* P_FI  = STATS + 14336;

  ushort* XTb   = (ushort*)XTBf;
  ushort* CAT2b = (ushort*)CAT2Bf;
  ushort* POOLb = (ushort*)POOLBf;
  ushort* CAT1b = (ushort*)OFFS;
  ushort* T3b   = (ushort*)R2;

  ushort* WPu = (ushort*)WPf;
  ushort* wp_lp2 = WPu;
  ushort* wp_c3  = wp_lp2 + 18432;
  ushort* wp_k2  = wp_c3 + 55296;
  ushort* wp_k3  = wp_k2 + 110592;
  ushort* wp_k4  = wp_k3 + 110592;

  const long bs64 = 64L * N, bs32 = 32L * N, bs96 = 96L * N;

  WArgs wa;
  wa.e[0] = { w_lp2, wp_lp2, 32, 32, 32, 64 * 9 * 32 };
  wa.e[1] = { w_c3,  wp_c3,  32, 96, 96, 64 * 9 * 96 };
  wa.e[2] = { w_k2,  wp_k2, 166, 64, 64, 192 * 9 * 64 };
  wa.e[3] = { w_k3,  wp_k3, 166, 64, 64, 192 * 9 * 64 };
  wa.e[4] = { w_k4,  wp_k4, 166, 166, 192, 192 * 9 * 192 };
  k_wpack<<<dim3(64, 5), 256, 0, stream>>>(wa);
  k_prep<<<dim3(N / 256, B), 256, 0, stream>>>(
      fx, fy, ln_g, ln_b, CAT2, XTb, CAT2b, XN, POOLb);
  k_conv1x1v<4><<<dim3(N / 1024, 24, B), 256, 0, stream>>>(
      XN, bs32, 32, w_qkv, nullptr, QKV1, bs96, 0, nullptr, 0);
  k_dwconv<<<dim3(N / 1024, 32, B), 256, 0, stream>>>(QKV1, w_qkvd, QKV2);
  k_attn_part<4><<<dim3(8, B, 16), 256, 0, stream>>>(
      QKV2, bs96, nullptr, 0, QKV2 + bs32, bs96, P_IN);
  k_attn_soft<4><<<dim3(8, B), 128, 0, stream>>>(P_IN, w_tempin, ST_IN);
  k_fold<4><<<dim3(B), 256, 0, stream>>>(ST_IN, w_mproj, M_IN);
  k_attn_mproj2<<<dim3(N / 256, B, 2), 256, 0, stream>>>(QKV2, M_IN, CAT2, CAT1b);
  k_conv1x1v<2><<<dim3(N / 512, 8, B), 256, 0, stream>>>(
      CAT2, bs64, 32, w_lp1, nullptr, nullptr, 0, 0, CAT1b, 96);
  // l2 -> CAT1b ch 32..63 (bf16 NHWC), 32 couts/block -> 1 y-tile
  k_conv3m<<<dim3(64, 1, B), 256, 0, stream>>>(
      CAT2b, (long)N * 64, 64, H, W, wp_lp2, 1, 32, CAT1b, 0, 32, H, W, 1, 1, 96, 32,
      nullptr);
  // prompt = c3(CAT1b) fp32 NCHW
  k_conv3m<<<dim3(64, 1, B), 256, 0, stream>>>(
      CAT1b, (long)N * 96, 96, H, W, wp_c3, 3, 32, PROMPT, bs32, 0, H, W, 1, 0, 0, 0,
      nullptr);
  // k2 -> ASMALL fp32 NHWC [B,3844,168]: 6 cout-tiles
  k_conv3m<<<dim3(31, 6, B), 256, 0, stream>>>(
      POOLb, 4096L * 64, 64, 64, 64, wp_k2, 2, 166, ASMALL, 0, 0, 62, 62, 0, 2, 168, 168,
      nullptr);
  // k3 -> T3b bf16 NHWC + fused sigmoid gate: 6 cout-tiles
  k_conv3m<<<dim3(64, 6, B), 256, 0, stream>>>(
      CAT2b, (long)N * 64, 64, H, W, wp_k3, 2, 166, T3b, 0, 0, H, W, 1, 1, 192, 192,
      ASMALL);
  // k4 -> OFFS fp32 NHWC [B,N,168]: 6 cout-tiles
  k_conv3m<<<dim3(64, 6, B), 256, 0, stream>>>(
      T3b, (long)N * 192, 192, H, W, wp_k4, 6, 166, OFFS, 0, 0, H, W, 1, 2, 168, 168,
      nullptr);
  // merged deformable conv v7
  {
    const int K2m = 49;
    const size_t smem = (size_t)K2m * 128 * 2 + (size_t)32 * K2m * 4 * 2 * 2;  // 37632
    k_deform7<<<dim3(3 * (N / 32), B), 256, smem, stream>>>(
        XTb, OFFS, w_d3, b_d3, w_d5, b_d5, w_d7, b_d7, CAT3);
  }
  k_conv1x1v<2><<<dim3(N / 512, 8, B), 256, 0, stream>>>(
      CAT3, bs96, 96, w_pw, b_pw, KFEAT, bs32, 0, nullptr, 0);
  k_attn_part<8><<<dim3(8, B, 16), 256, 0, stream>>>(
      CAT2, bs64, PROMPT, bs32, KFEAT, bs32, P_FI);
  k_attn_soft<8><<<dim3(8, B), 128, 0, stream>>>(P_FI, w_temp, ST_FI);
  k_fold<8><<<dim3(B), 256, 0, stream>>>(ST_FI, w_po, M_FI);
  k_attn_po2<<<dim3(N / 256, B, 2), 256, 0, stream>>>(CAT2, M_FI, (float*)d_out);
}

// Round 18
// 409.084 us; speedup vs baseline: 1.2089x; 1.0789x over previous
//
#include <hip/hip_runtime.h>
#include <hip/hip_bf16.h>
#include <hip/hip_fp16.h>

// ---------------------------------------------------------------------------
// MDTA_FOR_VIDEO_Prompted — full-graph HIP implementation.
// B=2, C=32, H=W=128. fp32 in/out; 3x3 convs via bf16 MFMA implicit GEMM.
// R18: 1x1 convs (qkv, pw) via barrier-free MFMA GEMM on bf16-NHWC inputs
//      (XNb from prep, CAT3b from deform). fp32 XN and CAT3 eliminated.
// ---------------------------------------------------------------------------

constexpr int B = 2, C = 32, H = 128, W = 128, N = H * W;

using bh8   = __attribute__((ext_vector_type(8))) short;
using f32x4 = __attribute__((ext_vector_type(4))) float;

__device__ __forceinline__ ushort f2bf(float v) {
  __hip_bfloat16 h = __float2bfloat16(v);
  return *(ushort*)&h;
}
__device__ __forceinline__ float bf2f(ushort u) {
  union { unsigned int i; float f; } w; w.i = ((unsigned int)u) << 16; return w.f;
}

// ---------------- prep (+ fused avgpool; XNb bf16 NHWC) ---------------------
__global__ __launch_bounds__(256) void k_prep(const float* __restrict__ x,
                                              const float* __restrict__ y,
                                              const float* __restrict__ ln_g,
                                              const float* __restrict__ ln_b,
                                              float* __restrict__ cat2,
                                              ushort* __restrict__ xtb,
                                              ushort* __restrict__ cat2b,
                                              ushort* __restrict__ xnb,
                                              ushort* __restrict__ poolb) {
  __shared__ float tile[C][257];
  const int b = blockIdx.y, n0 = blockIdx.x * 256, tid = threadIdx.x;
  const int n = n0 + tid;
  const int prow = blockIdx.x;
  for (int c = 0; c < C; c++) {
    float v = x[(size_t)(b * C + c) * N + n];
    tile[c][tid] = v;
    cat2[(size_t)(b * 64 + c) * N + n] = v;
  }
  __syncthreads();
  {
    float s = 0.f, ss = 0.f;
#pragma unroll
    for (int c = 0; c < C; c++) { const float v = tile[c][tid]; s += v; ss += v * v; }
    const float mu = s * (1.f / C);
    const float var = ss * (1.f / C) - mu * mu;
    const float inv = rsqrtf(var + 1e-5f);
    ushort xo[32];
#pragma unroll
    for (int c = 0; c < C; c++)
      xo[c] = f2bf((tile[c][tid] - mu) * inv * ln_g[c] + ln_b[c]);
    ushort* dp = xnb + ((size_t)b * N + n) * 32;
#pragma unroll
    for (int k = 0; k < 4; k++) *(bh8*)(dp + k * 8) = *(const bh8*)&xo[k * 8];
  }
  for (int i = tid; i < C * 256; i += 256) {
    int c = i & 31, nl = i >> 5;
    const ushort bv = f2bf(tile[c][nl]);
    xtb[((size_t)b * N + n0 + nl) * 32 + c] = bv;
    cat2b[((size_t)b * N + n0 + nl) * 64 + c] = bv;
  }
  for (int i = tid; i < 2048; i += 256) {
    const int ox = i >> 5, c = i & 31;
    const float pv = 0.25f * (tile[c][2 * ox] + tile[c][2 * ox + 1]
                            + tile[c][128 + 2 * ox] + tile[c][128 + 2 * ox + 1]);
    poolb[((size_t)b * 4096 + prow * 64 + ox) * 64 + c] = f2bf(pv);
  }
  __syncthreads();
  for (int c = 0; c < C; c++) {
    float v = y[(size_t)(b * C + c) * N + n];
    tile[c][tid] = v;
    cat2[(size_t)(b * 64 + 32 + c) * N + n] = v;
  }
  __syncthreads();
  for (int i = tid; i < C * 256; i += 256) {
    int c = i & 31, nl = i >> 5;
    cat2b[((size_t)b * N + n0 + nl) * 64 + 32 + c] = f2bf(tile[c][nl]);
  }
  for (int i = tid; i < 2048; i += 256) {
    const int ox = i >> 5, c = i & 31;
    const float pv = 0.25f * (tile[c][2 * ox] + tile[c][2 * ox + 1]
                            + tile[c][128 + 2 * ox] + tile[c][128 + 2 * ox + 1]);
    poolb[((size_t)b * 4096 + prow * 64 + ox) * 64 + 32 + c] = f2bf(pv);
  }
}

// ---------------- weight pack (3x3 convs, tap-major) ------------------------
struct WEnt { const float* src; ushort* dst; int cout_real, cin_real, kc32, total; };
struct WArgs { WEnt e[5]; };

__global__ __launch_bounds__(256) void k_wpack(WArgs a) {
  const WEnt en = a.e[blockIdx.y];
  const int tk = 9 * en.kc32;
  for (int i = blockIdx.x * 256 + threadIdx.x; i < en.total; i += gridDim.x * 256) {
    const int co = i / tk, rem = i - co * tk;
    const int t = rem / en.kc32, ci = rem - t * en.kc32;
    float v = 0.f;
    if (co < en.cout_real && ci < en.cin_real)
      v = en.src[((size_t)co * en.cin_real + ci) * 9 + t];
    en.dst[i] = f2bf(v);
  }
}

// ---------------- flat weight cast (1x1 convs) ------------------------------
__global__ __launch_bounds__(256)
void k_castw(const float* __restrict__ a, ushort* __restrict__ da, int na,
             const float* __restrict__ b2, ushort* __restrict__ db, int nb2) {
  const int i = blockIdx.x * 256 + threadIdx.x;
  if (i < na) da[i] = f2bf(a[i]);
  if (i < nb2) db[i] = f2bf(b2[i]);
}

// ---------------- 1x1 conv via MFMA (barrier-free) --------------------------
// in: bf16 NHWC (stride in_cs), wq: bf16 [co][KC*32], out: fp32 NCHW.
// wave = 16 px, block = 64 px.
template <int MT, int KC>
__global__ __launch_bounds__(256)
void k_gemm1x1(const ushort* __restrict__ in, int in_cs,
               const ushort* __restrict__ wq, const float* __restrict__ bias,
               float* __restrict__ out, long out_bs) {
  const int tid = threadIdx.x, b = blockIdx.y;
  const int px0 = blockIdx.x * 64 + (tid >> 6) * 16;
  const int lane = tid & 63, q = lane >> 4, n = lane & 15, q8 = q * 8;
  f32x4 acc[MT];
#pragma unroll
  for (int mt = 0; mt < MT; mt++) acc[mt] = (f32x4){0.f, 0.f, 0.f, 0.f};
  const ushort* ib = in + (size_t)b * N * in_cs;
#pragma unroll
  for (int kc = 0; kc < KC; kc++) {
    const bh8 bb = *(const bh8*)(ib + (size_t)(px0 + n) * in_cs + kc * 32 + q8);
#pragma unroll
    for (int mt = 0; mt < MT; mt++) {
      const bh8 a = *(const bh8*)(wq + (size_t)(mt * 16 + n) * (KC * 32) + kc * 32 + q8);
      acc[mt] = __builtin_amdgcn_mfma_f32_16x16x32_bf16(a, bb, acc[mt], 0, 0, 0);
    }
  }
  float* ob = out + (size_t)b * out_bs;
#pragma unroll
  for (int mt = 0; mt < MT; mt++)
#pragma unroll
    for (int r = 0; r < 4; r++) {
      const int co = mt * 16 + q * 4 + r;
      const float bv = bias ? bias[co] : 0.f;
      ob[(size_t)co * N + px0 + n] = acc[mt][r] + bv;
    }
}

// ---------------- 3x3 conv MFMA implicit GEMM (32 couts/block) -------------
__global__ __launch_bounds__(256)
void k_conv3m(const ushort* __restrict__ xin, long in_bs, int in_cs, int ih, int iw,
              const ushort* __restrict__ wp, int kchunks, int cout_real,
              void* __restrict__ outp, long out_bs, int out_coff,
              int oh, int ow, int pad, int omode, int out_cs, int store_tot,
              const float* __restrict__ gatep) {
  __shared__ ushort smem[17408];
  ushort* xt = smem;
  const int tid = threadIdx.x, b = blockIdx.z;
  const int y0 = blockIdx.x * 2, co0 = blockIdx.y * 32;
  const int wv = tid >> 6, lane = tid & 63;
  const int row_sel = wv >> 1, col0 = (wv & 1) * 64;
  const int q = lane >> 4, n = lane & 15, q8 = q * 8;
  const int kc32 = kchunks * 32;
  const ushort* xb = xin + (size_t)b * in_bs;

  f32x4 acc[2][4];
#pragma unroll
  for (int mt = 0; mt < 2; mt++)
#pragma unroll
    for (int nb = 0; nb < 4; nb++) acc[mt][nb] = (f32x4){0.f, 0.f, 0.f, 0.f};

  for (int cc = 0; cc < kchunks; cc++) {
    __syncthreads();
    for (int i = tid; i < 2080; i += 256) {
      const int qq = i & 3, rc = i >> 2;
      const int r = rc / 130, c = rc - r * 130;
      const int yy = y0 - pad + r, xx = c - pad;
      bh8 v = {0, 0, 0, 0, 0, 0, 0, 0};
      if (yy >= 0 && yy < ih && xx >= 0 && xx < iw)
        v = *(const bh8*)(xb + ((size_t)yy * iw + xx) * in_cs + cc * 32 + qq * 8);
      *(bh8*)&xt[rc * 32 + qq * 8] = v;
    }
    __syncthreads();
#pragma unroll
    for (int t = 0; t < 9; t++) {
      const int dy = t / 3, dx = t - dy * 3;
      bh8 a[2], bb[4];
#pragma unroll
      for (int mt = 0; mt < 2; mt++)
        a[mt] = *(const bh8*)(wp + (size_t)((co0 + mt * 16 + n) * 9 + t) * kc32 + cc * 32 + q8);
#pragma unroll
      for (int nb = 0; nb < 4; nb++)
        bb[nb] = *(const bh8*)&xt[((row_sel + dy) * 130 + col0 + nb * 16 + n + dx) * 32 + q8];
#pragma unroll
      for (int mt = 0; mt < 2; mt++)
#pragma unroll
        for (int nb = 0; nb < 4; nb++)
          acc[mt][nb] = __builtin_amdgcn_mfma_f32_16x16x32_bf16(a[mt], bb[nb], acc[mt][nb], 0, 0, 0);
    }
  }

  const size_t osp = (size_t)oh * ow;
  if (omode == 0) {
    const int oy = y0 + row_sel;
    float* ob = (float*)outp + (size_t)b * out_bs + (size_t)out_coff * osp + (size_t)oy * ow;
#pragma unroll
    for (int mt = 0; mt < 2; mt++)
#pragma unroll
      for (int r = 0; r < 4; r++) {
        const int co = co0 + mt * 16 + q * 4 + r;
        if (co < cout_real) {
#pragma unroll
          for (int nb = 0; nb < 4; nb++) {
            const int px = col0 + nb * 16 + n;
            if (px < ow) ob[(size_t)co * osp + px] = acc[mt][nb][r];
          }
        }
      }
  } else if (omode == 1) {
    __syncthreads();
#pragma unroll
    for (int mt = 0; mt < 2; mt++)
#pragma unroll
      for (int nb = 0; nb < 4; nb++) {
        const int px = col0 + nb * 16 + n;
        ushort4 o;
        o.x = f2bf(acc[mt][nb][0]); o.y = f2bf(acc[mt][nb][1]);
        o.z = f2bf(acc[mt][nb][2]); o.w = f2bf(acc[mt][nb][3]);
        *(ushort4*)&smem[(row_sel * 128 + px) * 36 + mt * 16 + q * 4] = o;
      }
    __syncthreads();
    {
      const int row = tid >> 7, px = tid & 127;
      const int oy2 = y0 + row;
      const int sc = min(32, store_tot - co0);
      if (px < ow && sc > 0) {
        ushort* dst = (ushort*)outp + ((size_t)b * osp + (size_t)oy2 * ow + px) * out_cs
                      + out_coff + co0;
        const ushort* src = &smem[(row * 128 + px) * 36];
        if (gatep) {
          const int iy = (oy2 * 62) >> 7, ix2 = (px * 62) >> 7;
          const float* gp = gatep + ((size_t)b * 3844 + iy * 62 + ix2) * 168;
          for (int c = 0; c < sc; c += 4) {
            ushort4 v = *(const ushort4*)(src + c);
            const int ch0 = out_coff + co0 + c;
            float g0 = 1.f, g1 = 1.f, g2 = 1.f, g3 = 1.f;
            if (ch0 + 3 < 166) {
              const float4 a4 = *(const float4*)(gp + ch0);
              g0 = 1.f / (1.f + expf(-a4.x)); g1 = 1.f / (1.f + expf(-a4.y));
              g2 = 1.f / (1.f + expf(-a4.z)); g3 = 1.f / (1.f + expf(-a4.w));
            } else {
              if (ch0 + 0 < 166) g0 = 1.f / (1.f + expf(-gp[ch0 + 0]));
              if (ch0 + 1 < 166) g1 = 1.f / (1.f + expf(-gp[ch0 + 1]));
              if (ch0 + 2 < 166) g2 = 1.f / (1.f + expf(-gp[ch0 + 2]));
              if (ch0 + 3 < 166) g3 = 1.f / (1.f + expf(-gp[ch0 + 3]));
            }
            v.x = f2bf(bf2f(v.x) * g0); v.y = f2bf(bf2f(v.y) * g1);
            v.z = f2bf(bf2f(v.z) * g2); v.w = f2bf(bf2f(v.w) * g3);
            *(ushort4*)(dst + c) = v;
          }
        } else {
          for (int c = 0; c < sc; c += 4)
            *(ushort4*)(dst + c) = *(const ushort4*)(src + c);
        }
      }
    }
  } else {
    float* tf = (float*)smem;
    for (int round = 0; round < 2; round++) {
      __syncthreads();
      if (row_sel == round) {
#pragma unroll
        for (int mt = 0; mt < 2; mt++)
#pragma unroll
          for (int nb = 0; nb < 4; nb++) {
            const int px = col0 + nb * 16 + n;
            *(f32x4*)&tf[px * 34 + mt * 16 + q * 4] = acc[mt][nb];
          }
      }
      __syncthreads();
      const int px = tid & 127, half = tid >> 7;
      const int oy2 = y0 + round;
      if (px < ow) {
        float* dst = (float*)outp + ((size_t)b * osp + (size_t)oy2 * ow + px) * out_cs
                     + out_coff + co0 + half * 16;
        const float* src = &tf[px * 34 + half * 16];
        for (int c = 0; c < 16; c += 4) {
          if (co0 + half * 16 + c + 3 < store_tot)
            *(float4*)(dst + c) = *(const float4*)(src + c);
        }
      }
    }
  }
}

// ---------------- 1x1 conv: PX px/thread, 4 couts (fp32 VALU) --------------
template <int PX>
__global__ __launch_bounds__(256)
void k_conv1x1v(const float* __restrict__ in, long in_bs, int cin,
                const float* __restrict__ wts, const float* __restrict__ bias,
                float* __restrict__ out, long out_bs, int out_coff,
                ushort* __restrict__ outb, int ob_cs) {
  const int n0 = (blockIdx.x * 256 + threadIdx.x) * PX;
  const int co0 = blockIdx.y * 4, b = blockIdx.z;
  const float* ip = in + (size_t)b * in_bs + n0;
  const float* w = wts + (size_t)co0 * cin;
  float acc[4][PX] = {};
  for (int ci = 0; ci < cin; ci++) {
    float xv[PX];
    if (PX == 4) {
      const float4 v = *(const float4*)(ip + (size_t)ci * N);
      xv[0] = v.x; xv[1] = v.y; xv[2] = v.z; xv[3] = v.w;
    } else {
      const float2 v = *(const float2*)(ip + (size_t)ci * N);
      xv[0] = v.x; xv[1] = v.y;
    }
    const float w0 = w[ci], w1 = w[cin + ci], w2 = w[2 * cin + ci], w3 = w[3 * cin + ci];
#pragma unroll
    for (int p = 0; p < PX; p++) {
      acc[0][p] += xv[p] * w0; acc[1][p] += xv[p] * w1;
      acc[2][p] += xv[p] * w2; acc[3][p] += xv[p] * w3;
    }
  }
  if (bias) {
#pragma unroll
    for (int o = 0; o < 4; o++) {
      const float bv = bias[co0 + o];
#pragma unroll
      for (int p = 0; p < PX; p++) acc[o][p] += bv;
    }
  }
  if (outb) {
#pragma unroll
    for (int p = 0; p < PX; p++) {
      ushort4 o;
      o.x = f2bf(acc[0][p]); o.y = f2bf(acc[1][p]);
      o.z = f2bf(acc[2][p]); o.w = f2bf(acc[3][p]);
      *(ushort4*)(outb + ((size_t)b * N + n0 + p) * ob_cs + out_coff + co0) = o;
    }
  } else {
#pragma unroll
    for (int o = 0; o < 4; o++) {
      if (PX == 4)
        *(float4*)(out + (size_t)b * out_bs + (size_t)(out_coff + co0 + o) * N + n0) =
            make_float4(acc[o][0], acc[o][1], acc[o][2], acc[o][3]);
      else
        *(float2*)(out + (size_t)b * out_bs + (size_t)(out_coff + co0 + o) * N + n0) =
            make_float2(acc[o][0], acc[o][1]);
    }
  }
}

// ---------------- grouped 3x3 conv: 4 px/thread ----------------------------
__global__ __launch_bounds__(256) void k_dwconv(const float* __restrict__ in,
                                                const float* __restrict__ wts,
                                                float* __restrict__ out) {
  const int n0 = (blockIdx.x * 256 + threadIdx.x) * 4;
  const int g = blockIdx.y, b = blockIdx.z;
  const int h0 = n0 >> 7, w0 = n0 & 127;
  float acc[3][4] = {};
  for (int ci = 0; ci < 3; ci++) {
    const float* ip = in + ((size_t)b * 96 + g * 3 + ci) * N;
    float v[3][6];
#pragma unroll
    for (int r = 0; r < 3; r++) {
      const int iy = h0 - 1 + r;
      const bool rowok = (iy >= 0) & (iy < H);
#pragma unroll
      for (int j = 0; j < 6; j++) {
        const int ix = w0 - 1 + j;
        v[r][j] = (rowok && ix >= 0 && ix < W) ? ip[(size_t)iy * W + ix] : 0.f;
      }
    }
#pragma unroll
    for (int o = 0; o < 3; o++) {
      const float* wp = wts + ((size_t)(g * 3 + o) * 3 + ci) * 9;
#pragma unroll
      for (int r = 0; r < 3; r++) {
        const float wa = wp[r * 3 + 0], wb = wp[r * 3 + 1], wc = wp[r * 3 + 2];
#pragma unroll
        for (int p = 0; p < 4; p++)
          acc[o][p] += v[r][p] * wa + v[r][p + 1] * wb + v[r][p + 2] * wc;
      }
    }
  }
#pragma unroll
  for (int o = 0; o < 3; o++)
    *(float4*)(out + ((size_t)b * 96 + g * 3 + o) * N + n0) =
        make_float4(acc[o][0], acc[o][1], acc[o][2], acc[o][3]);
}

// ---------------- channel-attn phase 1 (16 N-chunks) -----------------------
template <int DQ>
__global__ __launch_bounds__(256)
void k_attn_part(const float* __restrict__ q1, long q1_bs,
                 const float* __restrict__ q2, long q2_bs,
                 const float* __restrict__ k, long k_bs,
                 float* __restrict__ partial) {
  const int h = blockIdx.x, b = blockIdx.y, ch = blockIdx.z, tid = threadIdx.x;
  const float* qp[DQ];
#pragma unroll
  for (int d = 0; d < DQ; d++) {
    const int qc = h * DQ + d;
    qp[d] = (qc < 32) ? (q1 + (size_t)b * q1_bs + (size_t)qc * N)
                      : (q2 + (size_t)b * q2_bs + (size_t)(qc - 32) * N);
  }
  const float* kp[4];
#pragma unroll
  for (int e = 0; e < 4; e++) kp[e] = k + (size_t)b * k_bs + (size_t)(h * 4 + e) * N;

  constexpr int NV = DQ + 4 + DQ * 4;
  float ssq[DQ] = {}, ssk[4] = {}, gr[DQ][4] = {};
  const int n1 = (ch + 1) * (N / 16);
  for (int n = ch * (N / 16) + tid; n < n1; n += 256) {
    float qv[DQ], kv[4];
#pragma unroll
    for (int d = 0; d < DQ; d++) { qv[d] = qp[d][n]; ssq[d] += qv[d] * qv[d]; }
#pragma unroll
    for (int e = 0; e < 4; e++) { kv[e] = kp[e][n]; ssk[e] += kv[e] * kv[e]; }
#pragma unroll
    for (int d = 0; d < DQ; d++)
#pragma unroll
      for (int e = 0; e < 4; e++) gr[d][e] += qv[d] * kv[e];
  }
  float vals[NV];
#pragma unroll
  for (int d = 0; d < DQ; d++) vals[d] = ssq[d];
#pragma unroll
  for (int e = 0; e < 4; e++) vals[DQ + e] = ssk[e];
#pragma unroll
  for (int d = 0; d < DQ; d++)
#pragma unroll
    for (int e = 0; e < 4; e++) vals[DQ + 4 + d * 4 + e] = gr[d][e];
#pragma unroll
  for (int j = 0; j < NV; j++) {
    float v = vals[j];
    for (int m = 32; m > 0; m >>= 1) v += __shfl_xor(v, m, 64);
    vals[j] = v;
  }
  __shared__ float red[4][NV];
  const int wid = tid >> 6, lane = tid & 63;
  if (lane == 0)
#pragma unroll
    for (int j = 0; j < NV; j++) red[wid][j] = vals[j];
  __syncthreads();
  if (tid < NV)
    partial[(size_t)(((b * 8 + h) * 16) + ch) * NV + tid] =
        red[0][tid] + red[1][tid] + red[2][tid] + red[3][tid];
}

// ---------------- channel-attn phase 2 -------------------------------------
template <int DQ>
__global__ __launch_bounds__(128)
void k_attn_soft(const float* __restrict__ partial,
                 const float* __restrict__ temp, float* __restrict__ stats) {
  constexpr int NV = DQ + 4 + DQ * 4;
  const int h = blockIdx.x, b = blockIdx.y, tid = threadIdx.x;
  __shared__ float tot[NV];
  if (tid < NV) {
    float s = 0.f;
#pragma unroll
    for (int ch = 0; ch < 16; ch++)
      s += partial[(size_t)(((b * 8 + h) * 16) + ch) * NV + tid];
    tot[tid] = s;
  }
  __syncthreads();
  if (tid == 0) {
    float invq[DQ], invk[4];
#pragma unroll
    for (int d = 0; d < DQ; d++) invq[d] = 1.f / fmaxf(sqrtf(tot[d]), 1e-12f);
#pragma unroll
    for (int e = 0; e < 4; e++) invk[e] = 1.f / fmaxf(sqrtf(tot[DQ + e]), 1e-12f);
    const float t = temp[h];
    float* sp = stats + (size_t)(b * 8 + h) * DQ * 4;
    for (int d = 0; d < DQ; d++) {
      float s[4], mx = -1e30f;
#pragma unroll
      for (int e = 0; e < 4; e++) {
        s[e] = tot[DQ + 4 + d * 4 + e] * invq[d] * invk[e] * t;
        mx = fmaxf(mx, s[e]);
      }
      float sum = 0.f;
#pragma unroll
      for (int e = 0; e < 4; e++) { s[e] = expf(s[e] - mx); sum += s[e]; }
#pragma unroll
      for (int e = 0; e < 4; e++) sp[d * 4 + e] = s[e] / sum;
    }
  }
}

// ---------------- fold: M[co][h*4+e] = sum_d w[co][h*DQ+d] * A[h][d][e] ----
template <int DQ>
__global__ __launch_bounds__(256)
void k_fold(const float* __restrict__ stats, const float* __restrict__ w,
            float* __restrict__ M) {
  const int b = blockIdx.x;
  for (int idx = threadIdx.x; idx < 1024; idx += 256) {
    const int co = idx >> 5, j = idx & 31;
    const int h = j >> 2, e = j & 3;
    const float* A = stats + ((size_t)b * 8 + h) * DQ * 4;
    const float* wr = w + co * (8 * DQ) + h * DQ;
    float s = 0.f;
#pragma unroll
    for (int d = 0; d < DQ; d++) s += wr[d] * A[d * 4 + e];
    M[((size_t)b * 32 + co) * 32 + j] = s;
  }
}

// ---------------- folded inner attn+mproj+residual -> CAT1b ----------------
__global__ __launch_bounds__(256)
void k_attn_mproj2(const float* __restrict__ qkv2, const float* __restrict__ M2,
                   const float* __restrict__ x, ushort* __restrict__ cat1b) {
  __shared__ float mls[512];
  const int tid = threadIdx.x, b = blockIdx.y, z = blockIdx.z;
  const int n = blockIdx.x * 256 + tid;
  for (int i = tid; i < 512; i += 256)
    mls[i] = M2[((size_t)b * 32 + z * 16) * 32 + i];
  __syncthreads();
  const float* vi = qkv2 + (size_t)b * (96L * N) + 64L * N;
  float vv[32];
#pragma unroll
  for (int ci = 0; ci < 32; ci++) vv[ci] = vi[(size_t)ci * N + n];
  ushort to[16];
  for (int o = 0; o < 16; o++) {
    const float* m = &mls[o * 32];
    float r = 0.f;
#pragma unroll
    for (int ci = 0; ci < 32; ci += 4) {
      const float4 w4 = *(const float4*)&m[ci];
      r += w4.x * vv[ci] + w4.y * vv[ci + 1] + w4.z * vv[ci + 2] + w4.w * vv[ci + 3];
    }
    r += x[(size_t)(b * 64 + z * 16 + o) * N + n];
    to[o] = f2bf(r);
  }
  ushort* dp = cat1b + ((size_t)b * N + n) * 96 + 64 + z * 16;
#pragma unroll
  for (int k = 0; k < 2; k++) *(bh8*)(dp + k * 8) = *(const bh8*)&to[k * 8];
}

// ---------------- folded final attn+po -> d_out ----------------------------
__global__ __launch_bounds__(256)
void k_attn_po2(const float* __restrict__ cat2, const float* __restrict__ M,
                float* __restrict__ outp) {
  __shared__ float mls[512];
  const int tid = threadIdx.x, b = blockIdx.y, z = blockIdx.z;
  const int n = blockIdx.x * 256 + tid;
  for (int i = tid; i < 512; i += 256)
    mls[i] = M[((size_t)b * 32 + z * 16) * 32 + i];
  __syncthreads();
  const float* v = cat2 + (size_t)b * (64L * N);
  float vv[32];
#pragma unroll
  for (int ci = 0; ci < 32; ci++) vv[ci] = v[(size_t)ci * N + n];
  for (int o = 0; o < 16; o++) {
    const float* m = &mls[o * 32];
    float r = 0.f;
#pragma unroll
    for (int ci = 0; ci < 32; ci += 4) {
      const float4 w4 = *(const float4*)&m[ci];
      r += w4.x * vv[ci] + w4.y * vv[ci + 1] + w4.z * vv[ci + 2] + w4.w * vv[ci + 3];
    }
    outp[(size_t)(b * 32 + z * 16 + o) * N + n] = r;
  }
}

// ---------------- deformable conv v7 (-> CAT3b bf16 NHWC) -------------------
__global__ __launch_bounds__(256)
void k_deform7(const ushort* __restrict__ xtb, const float* __restrict__ offs,
               const float* __restrict__ wd3, const float* __restrict__ bd3,
               const float* __restrict__ wd5, const float* __restrict__ bd5,
               const float* __restrict__ wd7, const float* __restrict__ bd7,
               ushort* __restrict__ cat3b) {
  const int tid = threadIdx.x, b = blockIdx.y;
  const int zone = blockIdx.x >> 9;
  const int blk = blockIdx.x & 511;
  int K, off_c0, out_c0;
  const float *wd, *bd;
  if (zone == 0)      { K = 3; off_c0 = 0;  out_c0 = 0;  wd = wd3; bd = bd3; }
  else if (zone == 1) { K = 5; off_c0 = 18; out_c0 = 32; wd = wd5; bd = bd5; }
  else                { K = 7; off_c0 = 68; out_c0 = 64; wd = wd7; bd = bd7; }
  const int K2 = K * K, PAD = K / 2;

  extern __shared__ __align__(16) char smem[];
  __half*  wlds = (__half*)smem;
  __half*  wbl  = wlds + K2 * 128;
  ushort*  abl  = (ushort*)(wbl + 32 * K2 * 4);

  for (int i = tid; i < K2 * 128; i += 256) {
    const int t = i >> 7, r = i & 127;
    const int g = r >> 4, oo = (r >> 2) & 3, ci = r & 3;
    wlds[i] = __float2half(wd[(size_t)((g * 4 + oo) * 4 + ci) * K2 + t]);
  }
  const int px0 = blk * 32;
  const float* obb = offs + ((size_t)b * N) * 168;
  for (int i = tid; i < 32 * K2; i += 256) {
    const int p = i / K2, t = i - p * K2;
    const int px = px0 + p;
    const int hy = px >> 7, wx = px & 127;
    const int ky = t / K, kx = t - ky * K;
    const float* ob2 = obb + (size_t)px * 168 + off_c0;
    const float dy = ob2[2 * t];
    const float dx = ob2[2 * t + 1];
    const float py = (float)(hy - PAD + ky) + dy;
    const float pxf = (float)(wx - PAD + kx) + dx;
    const float y0f = floorf(py), x0f = floorf(pxf);
    const float fy = py - y0f, fx = pxf - x0f;
    const int y0 = (int)y0f, x0 = (int)x0f;
    const int y1 = y0 + 1, x1 = x0 + 1;
    float w00 = (1.f - fy) * (1.f - fx), w01 = (1.f - fy) * fx;
    float w10 = fy * (1.f - fx), w11 = fy * fx;
    const bool vy0 = (y0 >= 0) & (y0 < H), vy1 = (y1 >= 0) & (y1 < H);
    const bool vx0 = (x0 >= 0) & (x0 < W), vx1 = (x1 >= 0) & (x1 < W);
    w00 = (vy0 & vx0) ? w00 : 0.f;
    w01 = (vy0 & vx1) ? w01 : 0.f;
    w10 = (vy1 & vx0) ? w10 : 0.f;
    w11 = (vy1 & vx1) ? w11 : 0.f;
    const int cy0 = min(max(y0, 0), H - 1), cy1 = min(max(y1, 0), H - 1);
    const int cx0 = min(max(x0, 0), W - 1), cx1 = min(max(x1, 0), W - 1);
    const int base = (p * K2 + t) * 4;
    wbl[base + 0] = __float2half(w00); wbl[base + 1] = __float2half(w01);
    wbl[base + 2] = __float2half(w10); wbl[base + 3] = __float2half(w11);
    abl[base + 0] = (ushort)(cy0 * W + cx0);
    abl[base + 1] = (ushort)(cy0 * W + cx1);
    abl[base + 2] = (ushort)(cy1 * W + cx0);
    abl[base + 3] = (ushort)(cy1 * W + cx1);
  }
  __syncthreads();

  const int pxl = tid >> 3, g = tid & 7;
  const int px = px0 + pxl;
  const ushort* xb = xtb + (size_t)b * N * 32 + g * 4;
  float acc[4] = {0.f, 0.f, 0.f, 0.f};
  for (int t = 0; t < K2; t++) {
    const int base = (pxl * K2 + t) * 4;
    const ushort4 r4 = *(const ushort4*)&abl[base];
    const float2 w01v = __half22float2(*(const __half2*)&wbl[base]);
    const float2 w23v = __half22float2(*(const __half2*)&wbl[base + 2]);
    const ushort4 c0 = *(const ushort4*)(xb + (size_t)r4.x * 32);
    const ushort4 c1 = *(const ushort4*)(xb + (size_t)r4.y * 32);
    const ushort4 c2 = *(const ushort4*)(xb + (size_t)r4.z * 32);
    const ushort4 c3 = *(const ushort4*)(xb + (size_t)r4.w * 32);
    const float s0 = w01v.x * bf2f(c0.x) + w01v.y * bf2f(c1.x)
                   + w23v.x * bf2f(c2.x) + w23v.y * bf2f(c3.x);
    const float s1 = w01v.x * bf2f(c0.y) + w01v.y * bf2f(c1.y)
                   + w23v.x * bf2f(c2.y) + w23v.y * bf2f(c3.y);
    const float s2 = w01v.x * bf2f(c0.z) + w01v.y * bf2f(c1.z)
                   + w23v.x * bf2f(c2.z) + w23v.y * bf2f(c3.z);
    const float s3 = w01v.x * bf2f(c0.w) + w01v.y * bf2f(c1.w)
                   + w23v.x * bf2f(c2.w) + w23v.y * bf2f(c3.w);
    const __half2* wp2 = (const __half2*)&wlds[(t * 8 + g) * 16];
#pragma unroll
    for (int oo = 0; oo < 4; oo++) {
      const float2 u01 = __half22float2(wp2[oo * 2]);
      const float2 u23 = __half22float2(wp2[oo * 2 + 1]);
      acc[oo] += s0 * u01.x + s1 * u01.y + s2 * u23.x + s3 * u23.y;
    }
  }
  ushort4 o;
  o.x = f2bf(fmaxf(acc[0] + bd[g * 4 + 0], 0.f));
  o.y = f2bf(fmaxf(acc[1] + bd[g * 4 + 1], 0.f));
  o.z = f2bf(fmaxf(acc[2] + bd[g * 4 + 2], 0.f));
  o.w = f2bf(fmaxf(acc[3] + bd[g * 4 + 3], 0.f));
  *(ushort4*)(cat3b + ((size_t)b * N + px) * 96 + out_c0 + g * 4) = o;
}

// ---------------------------------------------------------------------------
extern "C" void kernel_launch(void* const* d_in, const int* in_sizes, int n_in,
                              void* d_out, int out_size, void* d_ws, size_t ws_size,
                              hipStream_t stream) {
  const float* fx       = (const float*)d_in[0];
  const float* fy       = (const float*)d_in[1];
  const float* w_temp   = (const float*)d_in[2];
  const float* w_po     = (const float*)d_in[3];
  const float* w_lp1    = (const float*)d_in[4];
  const float* w_lp2    = (const float*)d_in[5];
  const float* ln_g     = (const float*)d_in[6];
  const float* ln_b     = (const float*)d_in[7];
  const float* w_tempin = (const float*)d_in[8];
  const float* w_qkv    = (const float*)d_in[9];
  const float* w_qkvd   = (const float*)d_in[10];
  const float* w_mproj  = (const float*)d_in[11];
  const float* w_c3     = (const float*)d_in[12];
  const float* w_k2     = (const float*)d_in[13];
  const float* w_k3     = (const float*)d_in[14];
  const float* w_k4     = (const float*)d_in[15];
  const float* w_d3     = (const float*)d_in[16];
  const float* b_d3     = (const float*)d_in[17];
  const float* w_d5     = (const float*)d_in[18];
  const float* b_d5     = (const float*)d_in[19];
  const float* w_d7     = (const float*)d_in[20];
  const float* b_d7     = (const float*)d_in[21];
  const float* w_pw     = (const float*)d_in[22];
  const float* b_pw     = (const float*)d_in[23];
  float* ws = (float*)d_ws;

  size_t off = 0;
  auto buf = [&](size_t nelem) { float* p = ws + off; off += nelem; return p; };
  float* CAT2   = buf(2097152);
  float* XTBf   = buf(1048576);
  float* R1     = buf(1048576);   // XNb bf16 [B,N,32] (first half)
  float* R2     = buf(3145728);   // QKV1 -> T3b(bf16,192)
  float* R3     = buf(3145728);   // QKV2 -> ASMALL (fp32 NHWC [B,3844,168])
  float* PROMPT = buf(1048576);
  float* R4     = buf(5439488);   // CAT3b(bf16,96) + KFEAT
  float* OFFS   = buf(5505024);   // CAT1b(bf16,96) -> OFFS fp32 NHWC [B,N,168]
  float* STATS  = buf(65536);
  float* CAT2Bf = buf(524288);
  float* WPf    = buf(327680);
  float* POOLBf = buf(262144);
  (void)ws_size; (void)out_size; (void)n_in; (void)in_sizes;

  float* QKV1 = R2;
  float* QKV2 = R3;   float* ASMALL = R3 + 524288;
  float* KFEAT = R4 + 3145728;
  float* ST_IN = STATS;
  float* ST_FI = STATS + 256;
  float* M_IN  = STATS + 1024;
  float* M_FI  = STATS + 3072;
  float* P_IN  = STATS + 5120;
  float* P_FI  = STATS + 14336;

  ushort* XTb   = (ushort*)XTBf;
  ushort* XNb   = (ushort*)R1;     // [B,N,32]
  ushort* CAT2b = (ushort*)CAT2Bf;
  ushort* POOLb = (ushort*)POOLBf;
  ushort* CAT1b = (ushort*)OFFS;
  ushort* CAT3b = (ushort*)R4;     // [B,N,96] bf16
  ushort* T3b   = (ushort*)R2;

  ushort* WPu = (ushort*)WPf;
  ushort* wp_lp2 = WPu;
  ushort* wp_c3  = wp_lp2 + 18432;
  ushort* wp_k2  = wp_c3 + 55296;
  ushort* wp_k3  = wp_k2 + 110592;
  ushort* wp_k4  = wp_k3 + 110592;
  ushort* wq_qkv = wp_k4 + 331776;  // 96*32 = 3072
  ushort* wq_pw  = wq_qkv + 3072;   // 32*96 = 3072

  const long bs64 = 64L * N, bs32 = 32L * N, bs96 = 96L * N;

  WArgs wa;
  wa.e[0] = { w_lp2, wp_lp2, 32, 32, 32, 64 * 9 * 32 };
  wa.e[1] = { w_c3,  wp_c3,  32, 96, 96, 64 * 9 * 96 };
  wa.e[2] = { w_k2,  wp_k2, 166, 64, 64, 192 * 9 * 64 };
  wa.e[3] = { w_k3,  wp_k3, 166, 64, 64, 192 * 9 * 64 };
  wa.e[4] = { w_k4,  wp_k4, 166, 166, 192, 192 * 9 * 192 };
  k_wpack<<<dim3(64, 5), 256, 0, stream>>>(wa);
  k_castw<<<dim3(12), 256, 0, stream>>>(w_qkv, wq_qkv, 3072, w_pw, wq_pw, 3072);
  k_prep<<<dim3(N / 256, B), 256, 0, stream>>>(
      fx, fy, ln_g, ln_b, CAT2, XTb, CAT2b, XNb, POOLb);
  // qkv 1x1 via MFMA: XNb(bf16 NHWC 32) -> QKV1 fp32 NCHW (96)
  k_gemm1x1<6, 1><<<dim3(N / 64, B), 256, 0, stream>>>(
      XNb, 32, wq_qkv, nullptr, QKV1, bs96);
  k_dwconv<<<dim3(N / 1024, 32, B), 256, 0, stream>>>(QKV1, w_qkvd, QKV2);
  k_attn_part<4><<<dim3(8, B, 16), 256, 0, stream>>>(
      QKV2, bs96, nullptr, 0, QKV2 + bs32, bs96, P_IN);
  k_attn_soft<4><<<dim3(8, B), 128, 0, stream>>>(P_IN, w_tempin, ST_IN);
  k_fold<4><<<dim3(B), 256, 0, stream>>>(ST_IN, w_mproj, M_IN);
  k_attn_mproj2<<<dim3(N / 256, B, 2), 256, 0, stream>>>(QKV2, M_IN, CAT2, CAT1b);
  k_conv1x1v<2><<<dim3(N / 512, 8, B), 256, 0, stream>>>(
      CAT2, bs64, 32, w_lp1, nullptr, nullptr, 0, 0, CAT1b, 96);
  k_conv3m<<<dim3(64, 1, B), 256, 0, stream>>>(
      CAT2b, (long)N * 64, 64, H, W, wp_lp2, 1, 32, CAT1b, 0, 32, H, W, 1, 1, 96, 32,
      nullptr);
  k_conv3m<<<dim3(64, 1, B), 256, 0, stream>>>(
      CAT1b, (long)N * 96, 96, H, W, wp_c3, 3, 32, PROMPT, bs32, 0, H, W, 1, 0, 0, 0,
      nullptr);
  k_conv3m<<<dim3(31, 6, B), 256, 0, stream>>>(
      POOLb, 4096L * 64, 64, 64, 64, wp_k2, 2, 166, ASMALL, 0, 0, 62, 62, 0, 2, 168, 168,
      nullptr);
  k_conv3m<<<dim3(64, 6, B), 256, 0, stream>>>(
      CAT2b, (long)N * 64, 64, H, W, wp_k3, 2, 166, T3b, 0, 0, H, W, 1, 1, 192, 192,
      ASMALL);
  k_conv3m<<<dim3(64, 6, B), 256, 0, stream>>>(
      T3b, (long)N * 192, 192, H, W, wp_k4, 6, 166, OFFS, 0, 0, H, W, 1, 2, 168, 168,
      nullptr);
  // merged deformable conv v7 -> CAT3b (bf16 NHWC)
  {
    const int K2m = 49;
    const size_t smem = (size_t)K2m * 128 * 2 + (size_t)32 * K2m * 4 * 2 * 2;  // 37632
    k_deform7<<<dim3(3 * (N / 32), B), 256, smem, stream>>>(
        XTb, OFFS, w_d3, b_d3, w_d5, b_d5, w_d7, b_d7, CAT3b);
  }
  // pw 1x1 via MFMA: CAT3b(bf16 NHWC 96) -> KFEAT fp32 NCHW (32) + bias
  k_gemm1x1<2, 3><<<dim3(N / 64, B), 256, 0, stream>>>(
      CAT3b, 96, wq_pw, b_pw, KFEAT, bs32);
  k_attn_part<8><<<dim3(8, B, 16), 256, 0, stream>>>(
      CAT2, bs64, PROMPT, bs32, KFEAT, bs32, P_FI);
  k_attn_soft<8><<<dim3(8, B), 128, 0, stream>>>(P_FI, w_temp, ST_FI);
  k_fold<8><<<dim3(B), 256, 0, stream>>>(ST_FI, w_po, M_FI);
  k_attn_po2<<<dim3(N / 256, B, 2), 256, 0, stream>>>(CAT2, M_FI, (float*)d_out);
}

// Round 19
// 395.182 us; speedup vs baseline: 1.2514x; 1.0352x over previous
//
#include <hip/hip_runtime.h>
#include <hip/hip_bf16.h>
#include <hip/hip_fp16.h>

// ---------------------------------------------------------------------------
// MDTA_FOR_VIDEO_Prompted — full-graph HIP implementation.
// B=2, C=32, H=W=128. fp32 in/out; convs via bf16 MFMA.
// R19: dispatch-graph shrink: softfold (soft+fold), mproj_lp1 (lp1+mproj),
//      castw into wpack, dead y-half of fp32 CAT2 removed (X32).
// ---------------------------------------------------------------------------

constexpr int B = 2, C = 32, H = 128, W = 128, N = H * W;

using bh8   = __attribute__((ext_vector_type(8))) short;
using f32x4 = __attribute__((ext_vector_type(4))) float;

__device__ __forceinline__ ushort f2bf(float v) {
  __hip_bfloat16 h = __float2bfloat16(v);
  return *(ushort*)&h;
}
__device__ __forceinline__ float bf2f(ushort u) {
  union { unsigned int i; float f; } w; w.i = ((unsigned int)u) << 16; return w.f;
}

// ---------------- prep (+ fused avgpool; XNb bf16 NHWC; X32 fp32) ----------
__global__ __launch_bounds__(256) void k_prep(const float* __restrict__ x,
                                              const float* __restrict__ y,
                                              const float* __restrict__ ln_g,
                                              const float* __restrict__ ln_b,
                                              float* __restrict__ x32,
                                              ushort* __restrict__ xtb,
                                              ushort* __restrict__ cat2b,
                                              ushort* __restrict__ xnb,
                                              ushort* __restrict__ poolb) {
  __shared__ float tile[C][257];
  const int b = blockIdx.y, n0 = blockIdx.x * 256, tid = threadIdx.x;
  const int n = n0 + tid;
  const int prow = blockIdx.x;
  for (int c = 0; c < C; c++) {
    float v = x[(size_t)(b * C + c) * N + n];
    tile[c][tid] = v;
    x32[(size_t)(b * 32 + c) * N + n] = v;
  }
  __syncthreads();
  {
    float s = 0.f, ss = 0.f;
#pragma unroll
    for (int c = 0; c < C; c++) { const float v = tile[c][tid]; s += v; ss += v * v; }
    const float mu = s * (1.f / C);
    const float var = ss * (1.f / C) - mu * mu;
    const float inv = rsqrtf(var + 1e-5f);
    ushort xo[32];
#pragma unroll
    for (int c = 0; c < C; c++)
      xo[c] = f2bf((tile[c][tid] - mu) * inv * ln_g[c] + ln_b[c]);
    ushort* dp = xnb + ((size_t)b * N + n) * 32;
#pragma unroll
    for (int k = 0; k < 4; k++) *(bh8*)(dp + k * 8) = *(const bh8*)&xo[k * 8];
  }
  for (int i = tid; i < C * 256; i += 256) {
    int c = i & 31, nl = i >> 5;
    const ushort bv = f2bf(tile[c][nl]);
    xtb[((size_t)b * N + n0 + nl) * 32 + c] = bv;
    cat2b[((size_t)b * N + n0 + nl) * 64 + c] = bv;
  }
  for (int i = tid; i < 2048; i += 256) {
    const int ox = i >> 5, c = i & 31;
    const float pv = 0.25f * (tile[c][2 * ox] + tile[c][2 * ox + 1]
                            + tile[c][128 + 2 * ox] + tile[c][128 + 2 * ox + 1]);
    poolb[((size_t)b * 4096 + prow * 64 + ox) * 64 + c] = f2bf(pv);
  }
  __syncthreads();
  for (int c = 0; c < C; c++)
    tile[c][tid] = y[(size_t)(b * C + c) * N + n];
  __syncthreads();
  for (int i = tid; i < C * 256; i += 256) {
    int c = i & 31, nl = i >> 5;
    cat2b[((size_t)b * N + n0 + nl) * 64 + 32 + c] = f2bf(tile[c][nl]);
  }
  for (int i = tid; i < 2048; i += 256) {
    const int ox = i >> 5, c = i & 31;
    const float pv = 0.25f * (tile[c][2 * ox] + tile[c][2 * ox + 1]
                            + tile[c][128 + 2 * ox] + tile[c][128 + 2 * ox + 1]);
    poolb[((size_t)b * 4096 + prow * 64 + ox) * 64 + 32 + c] = f2bf(pv);
  }
}

// ---------------- weight pack (3x3 tap-major + flat 1x1) --------------------
struct WEnt { const float* src; ushort* dst; int cout_real, cin_real, kc32, total; };
struct WArgs { WEnt e[7]; };

__global__ __launch_bounds__(256) void k_wpack(WArgs a) {
  const WEnt en = a.e[blockIdx.y];
  if (en.kc32 == 0) {  // flat cast
    for (int i = blockIdx.x * 256 + threadIdx.x; i < en.total; i += gridDim.x * 256)
      en.dst[i] = f2bf(en.src[i]);
    return;
  }
  const int tk = 9 * en.kc32;
  for (int i = blockIdx.x * 256 + threadIdx.x; i < en.total; i += gridDim.x * 256) {
    const int co = i / tk, rem = i - co * tk;
    const int t = rem / en.kc32, ci = rem - t * en.kc32;
    float v = 0.f;
    if (co < en.cout_real && ci < en.cin_real)
      v = en.src[((size_t)co * en.cin_real + ci) * 9 + t];
    en.dst[i] = f2bf(v);
  }
}

// ---------------- 1x1 conv via MFMA (barrier-free) --------------------------
template <int MT, int KC>
__global__ __launch_bounds__(256)
void k_gemm1x1(const ushort* __restrict__ in, int in_cs,
               const ushort* __restrict__ wq, const float* __restrict__ bias,
               float* __restrict__ out, long out_bs) {
  const int tid = threadIdx.x, b = blockIdx.y;
  const int px0 = blockIdx.x * 64 + (tid >> 6) * 16;
  const int lane = tid & 63, q = lane >> 4, n = lane & 15, q8 = q * 8;
  f32x4 acc[MT];
#pragma unroll
  for (int mt = 0; mt < MT; mt++) acc[mt] = (f32x4){0.f, 0.f, 0.f, 0.f};
  const ushort* ib = in + (size_t)b * N * in_cs;
#pragma unroll
  for (int kc = 0; kc < KC; kc++) {
    const bh8 bb = *(const bh8*)(ib + (size_t)(px0 + n) * in_cs + kc * 32 + q8);
#pragma unroll
    for (int mt = 0; mt < MT; mt++) {
      const bh8 a = *(const bh8*)(wq + (size_t)(mt * 16 + n) * (KC * 32) + kc * 32 + q8);
      acc[mt] = __builtin_amdgcn_mfma_f32_16x16x32_bf16(a, bb, acc[mt], 0, 0, 0);
    }
  }
  float* ob = out + (size_t)b * out_bs;
#pragma unroll
  for (int mt = 0; mt < MT; mt++)
#pragma unroll
    for (int r = 0; r < 4; r++) {
      const int co = mt * 16 + q * 4 + r;
      const float bv = bias ? bias[co] : 0.f;
      ob[(size_t)co * N + px0 + n] = acc[mt][r] + bv;
    }
}

// ---------------- 3x3 conv MFMA implicit GEMM (32 couts/block) -------------
__global__ __launch_bounds__(256)
void k_conv3m(const ushort* __restrict__ xin, long in_bs, int in_cs, int ih, int iw,
              const ushort* __restrict__ wp, int kchunks, int cout_real,
              void* __restrict__ outp, long out_bs, int out_coff,
              int oh, int ow, int pad, int omode, int out_cs, int store_tot,
              const float* __restrict__ gatep) {
  __shared__ ushort smem[17408];
  ushort* xt = smem;
  const int tid = threadIdx.x, b = blockIdx.z;
  const int y0 = blockIdx.x * 2, co0 = blockIdx.y * 32;
  const int wv = tid >> 6, lane = tid & 63;
  const int row_sel = wv >> 1, col0 = (wv & 1) * 64;
  const int q = lane >> 4, n = lane & 15, q8 = q * 8;
  const int kc32 = kchunks * 32;
  const ushort* xb = xin + (size_t)b * in_bs;

  f32x4 acc[2][4];
#pragma unroll
  for (int mt = 0; mt < 2; mt++)
#pragma unroll
    for (int nb = 0; nb < 4; nb++) acc[mt][nb] = (f32x4){0.f, 0.f, 0.f, 0.f};

  for (int cc = 0; cc < kchunks; cc++) {
    __syncthreads();
    for (int i = tid; i < 2080; i += 256) {
      const int qq = i & 3, rc = i >> 2;
      const int r = rc / 130, c = rc - r * 130;
      const int yy = y0 - pad + r, xx = c - pad;
      bh8 v = {0, 0, 0, 0, 0, 0, 0, 0};
      if (yy >= 0 && yy < ih && xx >= 0 && xx < iw)
        v = *(const bh8*)(xb + ((size_t)yy * iw + xx) * in_cs + cc * 32 + qq * 8);
      *(bh8*)&xt[rc * 32 + qq * 8] = v;
    }
    __syncthreads();
#pragma unroll
    for (int t = 0; t < 9; t++) {
      const int dy = t / 3, dx = t - dy * 3;
      bh8 a[2], bb[4];
#pragma unroll
      for (int mt = 0; mt < 2; mt++)
        a[mt] = *(const bh8*)(wp + (size_t)((co0 + mt * 16 + n) * 9 + t) * kc32 + cc * 32 + q8);
#pragma unroll
      for (int nb = 0; nb < 4; nb++)
        bb[nb] = *(const bh8*)&xt[((row_sel + dy) * 130 + col0 + nb * 16 + n + dx) * 32 + q8];
#pragma unroll
      for (int mt = 0; mt < 2; mt++)
#pragma unroll
        for (int nb = 0; nb < 4; nb++)
          acc[mt][nb] = __builtin_amdgcn_mfma_f32_16x16x32_bf16(a[mt], bb[nb], acc[mt][nb], 0, 0, 0);
    }
  }

  const size_t osp = (size_t)oh * ow;
  if (omode == 0) {
    const int oy = y0 + row_sel;
    float* ob = (float*)outp + (size_t)b * out_bs + (size_t)out_coff * osp + (size_t)oy * ow;
#pragma unroll
    for (int mt = 0; mt < 2; mt++)
#pragma unroll
      for (int r = 0; r < 4; r++) {
        const int co = co0 + mt * 16 + q * 4 + r;
        if (co < cout_real) {
#pragma unroll
          for (int nb = 0; nb < 4; nb++) {
            const int px = col0 + nb * 16 + n;
            if (px < ow) ob[(size_t)co * osp + px] = acc[mt][nb][r];
          }
        }
      }
  } else if (omode == 1) {
    __syncthreads();
#pragma unroll
    for (int mt = 0; mt < 2; mt++)
#pragma unroll
      for (int nb = 0; nb < 4; nb++) {
        const int px = col0 + nb * 16 + n;
        ushort4 o;
        o.x = f2bf(acc[mt][nb][0]); o.y = f2bf(acc[mt][nb][1]);
        o.z = f2bf(acc[mt][nb][2]); o.w = f2bf(acc[mt][nb][3]);
        *(ushort4*)&smem[(row_sel * 128 + px) * 36 + mt * 16 + q * 4] = o;
      }
    __syncthreads();
    {
      const int row = tid >> 7, px = tid & 127;
      const int oy2 = y0 + row;
      const int sc = min(32, store_tot - co0);
      if (px < ow && sc > 0) {
        ushort* dst = (ushort*)outp + ((size_t)b * osp + (size_t)oy2 * ow + px) * out_cs
                      + out_coff + co0;
        const ushort* src = &smem[(row * 128 + px) * 36];
        if (gatep) {
          const int iy = (oy2 * 62) >> 7, ix2 = (px * 62) >> 7;
          const float* gp = gatep + ((size_t)b * 3844 + iy * 62 + ix2) * 168;
          for (int c = 0; c < sc; c += 4) {
            ushort4 v = *(const ushort4*)(src + c);
            const int ch0 = out_coff + co0 + c;
            float g0 = 1.f, g1 = 1.f, g2 = 1.f, g3 = 1.f;
            if (ch0 + 3 < 166) {
              const float4 a4 = *(const float4*)(gp + ch0);
              g0 = 1.f / (1.f + expf(-a4.x)); g1 = 1.f / (1.f + expf(-a4.y));
              g2 = 1.f / (1.f + expf(-a4.z)); g3 = 1.f / (1.f + expf(-a4.w));
            } else {
              if (ch0 + 0 < 166) g0 = 1.f / (1.f + expf(-gp[ch0 + 0]));
              if (ch0 + 1 < 166) g1 = 1.f / (1.f + expf(-gp[ch0 + 1]));
              if (ch0 + 2 < 166) g2 = 1.f / (1.f + expf(-gp[ch0 + 2]));
              if (ch0 + 3 < 166) g3 = 1.f / (1.f + expf(-gp[ch0 + 3]));
            }
            v.x = f2bf(bf2f(v.x) * g0); v.y = f2bf(bf2f(v.y) * g1);
            v.z = f2bf(bf2f(v.z) * g2); v.w = f2bf(bf2f(v.w) * g3);
            *(ushort4*)(dst + c) = v;
          }
        } else {
          for (int c = 0; c < sc; c += 4)
            *(ushort4*)(dst + c) = *(const ushort4*)(src + c);
        }
      }
    }
  } else {
    float* tf = (float*)smem;
    for (int round = 0; round < 2; round++) {
      __syncthreads();
      if (row_sel == round) {
#pragma unroll
        for (int mt = 0; mt < 2; mt++)
#pragma unroll
          for (int nb = 0; nb < 4; nb++) {
            const int px = col0 + nb * 16 + n;
            *(f32x4*)&tf[px * 34 + mt * 16 + q * 4] = acc[mt][nb];
          }
      }
      __syncthreads();
      const int px = tid & 127, half = tid >> 7;
      const int oy2 = y0 + round;
      if (px < ow) {
        float* dst = (float*)outp + ((size_t)b * osp + (size_t)oy2 * ow + px) * out_cs
                     + out_coff + co0 + half * 16;
        const float* src = &tf[px * 34 + half * 16];
        for (int c = 0; c < 16; c += 4) {
          if (co0 + half * 16 + c + 3 < store_tot)
            *(float4*)(dst + c) = *(const float4*)(src + c);
        }
      }
    }
  }
}

// ---------------- grouped 3x3 conv: 4 px/thread ----------------------------
__global__ __launch_bounds__(256) void k_dwconv(const float* __restrict__ in,
                                                const float* __restrict__ wts,
                                                float* __restrict__ out) {
  const int n0 = (blockIdx.x * 256 + threadIdx.x) * 4;
  const int g = blockIdx.y, b = blockIdx.z;
  const int h0 = n0 >> 7, w0 = n0 & 127;
  float acc[3][4] = {};
  for (int ci = 0; ci < 3; ci++) {
    const float* ip = in + ((size_t)b * 96 + g * 3 + ci) * N;
    float v[3][6];
#pragma unroll
    for (int r = 0; r < 3; r++) {
      const int iy = h0 - 1 + r;
      const bool rowok = (iy >= 0) & (iy < H);
#pragma unroll
      for (int j = 0; j < 6; j++) {
        const int ix = w0 - 1 + j;
        v[r][j] = (rowok && ix >= 0 && ix < W) ? ip[(size_t)iy * W + ix] : 0.f;
      }
    }
#pragma unroll
    for (int o = 0; o < 3; o++) {
      const float* wp = wts + ((size_t)(g * 3 + o) * 3 + ci) * 9;
#pragma unroll
      for (int r = 0; r < 3; r++) {
        const float wa = wp[r * 3 + 0], wb = wp[r * 3 + 1], wc = wp[r * 3 + 2];
#pragma unroll
        for (int p = 0; p < 4; p++)
          acc[o][p] += v[r][p] * wa + v[r][p + 1] * wb + v[r][p + 2] * wc;
      }
    }
  }
#pragma unroll
  for (int o = 0; o < 3; o++)
    *(float4*)(out + ((size_t)b * 96 + g * 3 + o) * N + n0) =
        make_float4(acc[o][0], acc[o][1], acc[o][2], acc[o][3]);
}

// ---------------- channel-attn phase 1 (16 N-chunks) -----------------------
template <int DQ>
__global__ __launch_bounds__(256)
void k_attn_part(const float* __restrict__ q1, long q1_bs,
                 const float* __restrict__ q2, long q2_bs,
                 const float* __restrict__ k, long k_bs,
                 float* __restrict__ partial) {
  const int h = blockIdx.x, b = blockIdx.y, ch = blockIdx.z, tid = threadIdx.x;
  const float* qp[DQ];
#pragma unroll
  for (int d = 0; d < DQ; d++) {
    const int qc = h * DQ + d;
    qp[d] = (qc < 32) ? (q1 + (size_t)b * q1_bs + (size_t)qc * N)
                      : (q2 + (size_t)b * q2_bs + (size_t)(qc - 32) * N);
  }
  const float* kp[4];
#pragma unroll
  for (int e = 0; e < 4; e++) kp[e] = k + (size_t)b * k_bs + (size_t)(h * 4 + e) * N;

  constexpr int NV = DQ + 4 + DQ * 4;
  float ssq[DQ] = {}, ssk[4] = {}, gr[DQ][4] = {};
  const int n1 = (ch + 1) * (N / 16);
  for (int n = ch * (N / 16) + tid; n < n1; n += 256) {
    float qv[DQ], kv[4];
#pragma unroll
    for (int d = 0; d < DQ; d++) { qv[d] = qp[d][n]; ssq[d] += qv[d] * qv[d]; }
#pragma unroll
    for (int e = 0; e < 4; e++) { kv[e] = kp[e][n]; ssk[e] += kv[e] * kv[e]; }
#pragma unroll
    for (int d = 0; d < DQ; d++)
#pragma unroll
      for (int e = 0; e < 4; e++) gr[d][e] += qv[d] * kv[e];
  }
  float vals[NV];
#pragma unroll
  for (int d = 0; d < DQ; d++) vals[d] = ssq[d];
#pragma unroll
  for (int e = 0; e < 4; e++) vals[DQ + e] = ssk[e];
#pragma unroll
  for (int d = 0; d < DQ; d++)
#pragma unroll
    for (int e = 0; e < 4; e++) vals[DQ + 4 + d * 4 + e] = gr[d][e];
#pragma unroll
  for (int j = 0; j < NV; j++) {
    float v = vals[j];
    for (int m = 32; m > 0; m >>= 1) v += __shfl_xor(v, m, 64);
    vals[j] = v;
  }
  __shared__ float red[4][NV];
  const int wid = tid >> 6, lane = tid & 63;
  if (lane == 0)
#pragma unroll
    for (int j = 0; j < NV; j++) red[wid][j] = vals[j];
  __syncthreads();
  if (tid < NV)
    partial[(size_t)(((b * 8 + h) * 16) + ch) * NV + tid] =
        red[0][tid] + red[1][tid] + red[2][tid] + red[3][tid];
}

// ---------------- merged softmax + fold: partial -> M column block ---------
template <int DQ>
__global__ __launch_bounds__(128)
void k_softfold(const float* __restrict__ partial, const float* __restrict__ temp,
                const float* __restrict__ w, float* __restrict__ M) {
  constexpr int NV = DQ + 4 + DQ * 4;
  const int h = blockIdx.x, b = blockIdx.y, tid = threadIdx.x;
  __shared__ float tot[NV];
  __shared__ float als[DQ * 4];
  if (tid < NV) {
    float s = 0.f;
#pragma unroll
    for (int ch = 0; ch < 16; ch++)
      s += partial[(size_t)(((b * 8 + h) * 16) + ch) * NV + tid];
    tot[tid] = s;
  }
  __syncthreads();
  if (tid == 0) {
    float invq[DQ], invk[4];
#pragma unroll
    for (int d = 0; d < DQ; d++) invq[d] = 1.f / fmaxf(sqrtf(tot[d]), 1e-12f);
#pragma unroll
    for (int e = 0; e < 4; e++) invk[e] = 1.f / fmaxf(sqrtf(tot[DQ + e]), 1e-12f);
    const float t = temp[h];
    for (int d = 0; d < DQ; d++) {
      float s[4], mx = -1e30f;
#pragma unroll
      for (int e = 0; e < 4; e++) {
        s[e] = tot[DQ + 4 + d * 4 + e] * invq[d] * invk[e] * t;
        mx = fmaxf(mx, s[e]);
      }
      float sum = 0.f;
#pragma unroll
      for (int e = 0; e < 4; e++) { s[e] = expf(s[e] - mx); sum += s[e]; }
#pragma unroll
      for (int e = 0; e < 4; e++) als[d * 4 + e] = s[e] / sum;
    }
  }
  __syncthreads();
  // each thread: one (co, e) of M's h-column block
  const int co = tid >> 2, e = tid & 3;
  const float* wr = w + co * (8 * DQ) + h * DQ;
  float s = 0.f;
#pragma unroll
  for (int d = 0; d < DQ; d++) s += wr[d] * als[d * 4 + e];
  M[((size_t)b * 32 + co) * 32 + h * 4 + e] = s;
}

// ---------------- merged lp1 + folded mproj -> CAT1b -----------------------
// z=0: ch 0..31 = W_lp1 . x ; z=1: ch 64..95 = M . vi + x
__global__ __launch_bounds__(256)
void k_mproj_lp1(const float* __restrict__ qkv2, const float* __restrict__ M2,
                 const float* __restrict__ w_lp1, const float* __restrict__ x32,
                 ushort* __restrict__ cat1b) {
  __shared__ float mls[1024];
  const int tid = threadIdx.x, b = blockIdx.y, z = blockIdx.z;
  const int n = blockIdx.x * 256 + tid;
  const float* msrc = (z == 0) ? w_lp1 : (M2 + (size_t)b * 1024);
  for (int i = tid; i < 1024; i += 256) mls[i] = msrc[i];
  __syncthreads();
  float vv[32];
  if (z == 0) {
#pragma unroll
    for (int ci = 0; ci < 32; ci++) vv[ci] = x32[(size_t)(b * 32 + ci) * N + n];
  } else {
    const float* vi = qkv2 + (size_t)b * (96L * N) + 64L * N;
#pragma unroll
    for (int ci = 0; ci < 32; ci++) vv[ci] = vi[(size_t)ci * N + n];
  }
  ushort to[32];
  for (int o = 0; o < 32; o++) {
    const float* m = &mls[o * 32];
    float r = 0.f;
#pragma unroll
    for (int ci = 0; ci < 32; ci += 4) {
      const float4 w4 = *(const float4*)&m[ci];
      r += w4.x * vv[ci] + w4.y * vv[ci + 1] + w4.z * vv[ci + 2] + w4.w * vv[ci + 3];
    }
    if (z == 1) r += x32[(size_t)(b * 32 + o) * N + n];
    to[o] = f2bf(r);
  }
  ushort* dp = cat1b + ((size_t)b * N + n) * 96 + (z ? 64 : 0);
#pragma unroll
  for (int k = 0; k < 4; k++) *(bh8*)(dp + k * 8) = *(const bh8*)&to[k * 8];
}

// ---------------- folded final attn+po -> d_out ----------------------------
__global__ __launch_bounds__(256)
void k_attn_po2(const float* __restrict__ x32, const float* __restrict__ M,
                float* __restrict__ outp) {
  __shared__ float mls[512];
  const int tid = threadIdx.x, b = blockIdx.y, z = blockIdx.z;
  const int n = blockIdx.x * 256 + tid;
  for (int i = tid; i < 512; i += 256)
    mls[i] = M[((size_t)b * 32 + z * 16) * 32 + i];
  __syncthreads();
  const float* v = x32 + (size_t)b * (32L * N);
  float vv[32];
#pragma unroll
  for (int ci = 0; ci < 32; ci++) vv[ci] = v[(size_t)ci * N + n];
  for (int o = 0; o < 16; o++) {
    const float* m = &mls[o * 32];
    float r = 0.f;
#pragma unroll
    for (int ci = 0; ci < 32; ci += 4) {
      const float4 w4 = *(const float4*)&m[ci];
      r += w4.x * vv[ci] + w4.y * vv[ci + 1] + w4.z * vv[ci + 2] + w4.w * vv[ci + 3];
    }
    outp[(size_t)(b * 32 + z * 16 + o) * N + n] = r;
  }
}

// ---------------- deformable conv v7 (-> CAT3b bf16 NHWC) -------------------
__global__ __launch_bounds__(256)
void k_deform7(const ushort* __restrict__ xtb, const float* __restrict__ offs,
               const float* __restrict__ wd3, const float* __restrict__ bd3,
               const float* __restrict__ wd5, const float* __restrict__ bd5,
               const float* __restrict__ wd7, const float* __restrict__ bd7,
               ushort* __restrict__ cat3b) {
  const int tid = threadIdx.x, b = blockIdx.y;
  const int zone = blockIdx.x >> 9;
  const int blk = blockIdx.x & 511;
  int K, off_c0, out_c0;
  const float *wd, *bd;
  if (zone == 0)      { K = 3; off_c0 = 0;  out_c0 = 0;  wd = wd3; bd = bd3; }
  else if (zone == 1) { K = 5; off_c0 = 18; out_c0 = 32; wd = wd5; bd = bd5; }
  else                { K = 7; off_c0 = 68; out_c0 = 64; wd = wd7; bd = bd7; }
  const int K2 = K * K, PAD = K / 2;

  extern __shared__ __align__(16) char smem[];
  __half*  wlds = (__half*)smem;
  __half*  wbl  = wlds + K2 * 128;
  ushort*  abl  = (ushort*)(wbl + 32 * K2 * 4);

  for (int i = tid; i < K2 * 128; i += 256) {
    const int t = i >> 7, r = i & 127;
    const int g = r >> 4, oo = (r >> 2) & 3, ci = r & 3;
    wlds[i] = __float2half(wd[(size_t)((g * 4 + oo) * 4 + ci) * K2 + t]);
  }
  const int px0 = blk * 32;
  const float* obb = offs + ((size_t)b * N) * 168;
  for (int i = tid; i < 32 * K2; i += 256) {
    const int p = i / K2, t = i - p * K2;
    const int px = px0 + p;
    const int hy = px >> 7, wx = px & 127;
    const int ky = t / K, kx = t - ky * K;
    const float* ob2 = obb + (size_t)px * 168 + off_c0;
    const float dy = ob2[2 * t];
    const float dx = ob2[2 * t + 1];
    const float py = (float)(hy - PAD + ky) + dy;
    const float pxf = (float)(wx - PAD + kx) + dx;
    const float y0f = floorf(py), x0f = floorf(pxf);
    const float fy = py - y0f, fx = pxf - x0f;
    const int y0 = (int)y0f, x0 = (int)x0f;
    const int y1 = y0 + 1, x1 = x0 + 1;
    float w00 = (1.f - fy) * (1.f - fx), w01 = (1.f - fy) * fx;
    float w10 = fy * (1.f - fx), w11 = fy * fx;
    const bool vy0 = (y0 >= 0) & (y0 < H), vy1 = (y1 >= 0) & (y1 < H);
    const bool vx0 = (x0 >= 0) & (x0 < W), vx1 = (x1 >= 0) & (x1 < W);
    w00 = (vy0 & vx0) ? w00 : 0.f;
    w01 = (vy0 & vx1) ? w01 : 0.f;
    w10 = (vy1 & vx0) ? w10 : 0.f;
    w11 = (vy1 & vx1) ? w11 : 0.f;
    const int cy0 = min(max(y0, 0), H - 1), cy1 = min(max(y1, 0), H - 1);
    const int cx0 = min(max(x0, 0), W - 1), cx1 = min(max(x1, 0), W - 1);
    const int base = (p * K2 + t) * 4;
    wbl[base + 0] = __float2half(w00); wbl[base + 1] = __float2half(w01);
    wbl[base + 2] = __float2half(w10); wbl[base + 3] = __float2half(w11);
    abl[base + 0] = (ushort)(cy0 * W + cx0);
    abl[base + 1] = (ushort)(cy0 * W + cx1);
    abl[base + 2] = (ushort)(cy1 * W + cx0);
    abl[base + 3] = (ushort)(cy1 * W + cx1);
  }
  __syncthreads();

  const int pxl = tid >> 3, g = tid & 7;
  const int px = px0 + pxl;
  const ushort* xb = xtb + (size_t)b * N * 32 + g * 4;
  float acc[4] = {0.f, 0.f, 0.f, 0.f};
  for (int t = 0; t < K2; t++) {
    const int base = (pxl * K2 + t) * 4;
    const ushort4 r4 = *(const ushort4*)&abl[base];
    const float2 w01v = __half22float2(*(const __half2*)&wbl[base]);
    const float2 w23v = __half22float2(*(const __half2*)&wbl[base + 2]);
    const ushort4 c0 = *(const ushort4*)(xb + (size_t)r4.x * 32);
    const ushort4 c1 = *(const ushort4*)(xb + (size_t)r4.y * 32);
    const ushort4 c2 = *(const ushort4*)(xb + (size_t)r4.z * 32);
    const ushort4 c3 = *(const ushort4*)(xb + (size_t)r4.w * 32);
    const float s0 = w01v.x * bf2f(c0.x) + w01v.y * bf2f(c1.x)
                   + w23v.x * bf2f(c2.x) + w23v.y * bf2f(c3.x);
    const float s1 = w01v.x * bf2f(c0.y) + w01v.y * bf2f(c1.y)
                   + w23v.x * bf2f(c2.y) + w23v.y * bf2f(c3.y);
    const float s2 = w01v.x * bf2f(c0.z) + w01v.y * bf2f(c1.z)
                   + w23v.x * bf2f(c2.z) + w23v.y * bf2f(c3.z);
    const float s3 = w01v.x * bf2f(c0.w) + w01v.y * bf2f(c1.w)
                   + w23v.x * bf2f(c2.w) + w23v.y * bf2f(c3.w);
    const __half2* wp2 = (const __half2*)&wlds[(t * 8 + g) * 16];
#pragma unroll
    for (int oo = 0; oo < 4; oo++) {
      const float2 u01 = __half22float2(wp2[oo * 2]);
      const float2 u23 = __half22float2(wp2[oo * 2 + 1]);
      acc[oo] += s0 * u01.x + s1 * u01.y + s2 * u23.x + s3 * u23.y;
    }
  }
  ushort4 o;
  o.x = f2bf(fmaxf(acc[0] + bd[g * 4 + 0], 0.f));
  o.y = f2bf(fmaxf(acc[1] + bd[g * 4 + 1], 0.f));
  o.z = f2bf(fmaxf(acc[2] + bd[g * 4 + 2], 0.f));
  o.w = f2bf(fmaxf(acc[3] + bd[g * 4 + 3], 0.f));
  *(ushort4*)(cat3b + ((size_t)b * N + px) * 96 + out_c0 + g * 4) = o;
}

// ---------------------------------------------------------------------------
extern "C" void kernel_launch(void* const* d_in, const int* in_sizes, int n_in,
                              void* d_out, int out_size, void* d_ws, size_t ws_size,
                              hipStream_t stream) {
  const float* fx       = (const float*)d_in[0];
  const float* fy       = (const float*)d_in[1];
  const float* w_temp   = (const float*)d_in[2];
  const float* w_po     = (const float*)d_in[3];
  const float* w_lp1    = (const float*)d_in[4];
  const float* w_lp2    = (const float*)d_in[5];
  const float* ln_g     = (const float*)d_in[6];
  const float* ln_b     = (const float*)d_in[7];
  const float* w_tempin = (const float*)d_in[8];
  const float* w_qkv    = (const float*)d_in[9];
  const float* w_qkvd   = (const float*)d_in[10];
  const float* w_mproj  = (const float*)d_in[11];
  const float* w_c3     = (const float*)d_in[12];
  const float* w_k2     = (const float*)d_in[13];
  const float* w_k3     = (const float*)d_in[14];
  const float* w_k4     = (const float*)d_in[15];
  const float* w_d3     = (const float*)d_in[16];
  const float* b_d3     = (const float*)d_in[17];
  const float* w_d5     = (const float*)d_in[18];
  const float* b_d5     = (const float*)d_in[19];
  const float* w_d7     = (const float*)d_in[20];
  const float* b_d7     = (const float*)d_in[21];
  const float* w_pw     = (const float*)d_in[22];
  const float* b_pw     = (const float*)d_in[23];
  float* ws = (float*)d_ws;

  size_t off = 0;
  auto buf = [&](size_t nelem) { float* p = ws + off; off += nelem; return p; };
  float* X32    = buf(1048576);   // [B,32,N] fp32 x
  float* XTBf   = buf(1048576);
  float* R1     = buf(1048576);   // XNb bf16 [B,N,32]
  float* R2     = buf(3145728);   // QKV1 -> T3b(bf16,192)
  float* R3     = buf(3145728);   // QKV2 -> ASMALL (fp32 NHWC [B,3844,168])
  float* PROMPT = buf(1048576);
  float* R4     = buf(5439488);   // CAT3b(bf16,96) + KFEAT
  float* OFFS   = buf(5505024);   // CAT1b(bf16,96) -> OFFS fp32 NHWC [B,N,168]
  float* STATS  = buf(65536);
  float* CAT2Bf = buf(524288);
  float* WPf    = buf(327680);
  float* POOLBf = buf(262144);
  (void)ws_size; (void)out_size; (void)n_in; (void)in_sizes;

  float* QKV1 = R2;
  float* QKV2 = R3;   float* ASMALL = R3 + 524288;
  float* KFEAT = R4 + 3145728;
  float* M_IN  = STATS + 1024;
  float* M_FI  = STATS + 3072;
  float* P_IN  = STATS + 5120;
  float* P_FI  = STATS + 14336;

  ushort* XTb   = (ushort*)XTBf;
  ushort* XNb   = (ushort*)R1;
  ushort* CAT2b = (ushort*)CAT2Bf;
  ushort* POOLb = (ushort*)POOLBf;
  ushort* CAT1b = (ushort*)OFFS;
  ushort* CAT3b = (ushort*)R4;
  ushort* T3b   = (ushort*)R2;

  ushort* WPu = (ushort*)WPf;
  ushort* wp_lp2 = WPu;
  ushort* wp_c3  = wp_lp2 + 18432;
  ushort* wp_k2  = wp_c3 + 55296;
  ushort* wp_k3  = wp_k2 + 110592;
  ushort* wp_k4  = wp_k3 + 110592;
  ushort* wq_qkv = wp_k4 + 331776;
  ushort* wq_pw  = wq_qkv + 3072;

  const long bs32 = 32L * N, bs96 = 96L * N;

  WArgs wa;
  wa.e[0] = { w_lp2, wp_lp2, 32, 32, 32, 64 * 9 * 32 };
  wa.e[1] = { w_c3,  wp_c3,  32, 96, 96, 64 * 9 * 96 };
  wa.e[2] = { w_k2,  wp_k2, 166, 64, 64, 192 * 9 * 64 };
  wa.e[3] = { w_k3,  wp_k3, 166, 64, 64, 192 * 9 * 64 };
  wa.e[4] = { w_k4,  wp_k4, 166, 166, 192, 192 * 9 * 192 };
  wa.e[5] = { w_qkv, wq_qkv, 0, 0, 0, 3072 };
  wa.e[6] = { w_pw,  wq_pw,  0, 0, 0, 3072 };
  k_wpack<<<dim3(64, 7), 256, 0, stream>>>(wa);
  k_prep<<<dim3(N / 256, B), 256, 0, stream>>>(
      fx, fy, ln_g, ln_b, X32, XTb, CAT2b, XNb, POOLb);
  k_gemm1x1<6, 1><<<dim3(N / 64, B), 256, 0, stream>>>(
      XNb, 32, wq_qkv, nullptr, QKV1, bs96);
  k_dwconv<<<dim3(N / 1024, 32, B), 256, 0, stream>>>(QKV1, w_qkvd, QKV2);
  k_attn_part<4><<<dim3(8, B, 16), 256, 0, stream>>>(
      QKV2, bs96, nullptr, 0, QKV2 + bs32, bs96, P_IN);
  k_softfold<4><<<dim3(8, B), 128, 0, stream>>>(P_IN, w_tempin, w_mproj, M_IN);
  k_mproj_lp1<<<dim3(N / 256, B, 2), 256, 0, stream>>>(QKV2, M_IN, w_lp1, X32, CAT1b);
  k_conv3m<<<dim3(64, 1, B), 256, 0, stream>>>(
      CAT2b, (long)N * 64, 64, H, W, wp_lp2, 1, 32, CAT1b, 0, 32, H, W, 1, 1, 96, 32,
      nullptr);
  k_conv3m<<<dim3(64, 1, B), 256, 0, stream>>>(
      CAT1b, (long)N * 96, 96, H, W, wp_c3, 3, 32, PROMPT, bs32, 0, H, W, 1, 0, 0, 0,
      nullptr);
  k_conv3m<<<dim3(31, 6, B), 256, 0, stream>>>(
      POOLb, 4096L * 64, 64, 64, 64, wp_k2, 2, 166, ASMALL, 0, 0, 62, 62, 0, 2, 168, 168,
      nullptr);
  k_conv3m<<<dim3(64, 6, B), 256, 0, stream>>>(
      CAT2b, (long)N * 64, 64, H, W, wp_k3, 2, 166, T3b, 0, 0, H, W, 1, 1, 192, 192,
      ASMALL);
  k_conv3m<<<dim3(64, 6, B), 256, 0, stream>>>(
      T3b, (long)N * 192, 192, H, W, wp_k4, 6, 166, OFFS, 0, 0, H, W, 1, 2, 168, 168,
      nullptr);
  {
    const int K2m = 49;
    const size_t smem = (size_t)K2m * 128 * 2 + (size_t)32 * K2m * 4 * 2 * 2;  // 37632
    k_deform7<<<dim3(3 * (N / 32), B), 256, smem, stream>>>(
        XTb, OFFS, w_d3, b_d3, w_d5, b_d5, w_d7, b_d7, CAT3b);
  }
  k_gemm1x1<2, 3><<<dim3(N / 64, B), 256, 0, stream>>>(
      CAT3b, 96, wq_pw, b_pw, KFEAT, bs32);
  k_attn_part<8><<<dim3(8, B, 16), 256, 0, stream>>>(
      X32, bs32, PROMPT, bs32, KFEAT, bs32, P_FI);
  k_softfold<8><<<dim3(8, B), 128, 0, stream>>>(P_FI, w_temp, w_po, M_FI);
  k_attn_po2<<<dim3(N / 256, B, 2), 256, 0, stream>>>(X32, M_FI, (float*)d_out);
}